// Round 12
// baseline (489.117 us; speedup 1.0000x reference)
//
#include <hip/hip_runtime.h>

#define DEV __device__ __forceinline__

typedef float          f32x4  __attribute__((ext_vector_type(4)));
typedef __bf16         bf16x8 __attribute__((ext_vector_type(8)));
typedef unsigned short u16x8  __attribute__((ext_vector_type(8)));

static constexpr int  Bq   = 256;   // batch
static constexpr int  Qs   = 128;   // seq len
static constexpr int  Dm   = 256;   // model dim
static constexpr int  Ff   = 512;   // ffn dim
static constexpr int  ROWS = Bq * Qs;               // 32768
static constexpr long QK_LSTR = (long)ROWS * 512;   // q||k history per layer (head-major)

DEV float b2f(unsigned short h) {
    unsigned int u = ((unsigned int)h) << 16;
    float f; __builtin_memcpy(&f, &u, 4); return f;
}
DEV unsigned short f2b(float f) {
    unsigned int u; __builtin_memcpy(&u, &f, 4);
    u += 0x7fffu + ((u >> 16) & 1u);   // RNE
    return (unsigned short)(u >> 16);
}
DEV f32x4 mfma_bf16(u16x8 a, u16x8 b, f32x4 c) {
    return __builtin_amdgcn_mfma_f32_16x16x32_bf16(
        __builtin_bit_cast(bf16x8, a), __builtin_bit_cast(bf16x8, b), c, 0, 0, 0);
}
// async global->LDS, 16B per lane; LDS dst must be wave-uniform base + lane*16
DEV void gl_lds16(const unsigned short* g, unsigned short* l) {
    __builtin_amdgcn_global_load_lds(
        (const __attribute__((address_space(1))) unsigned int*)g,
        (__attribute__((address_space(3))) unsigned int*)l, 16, 0, 0);
}
// XOR-chunk-swizzled LDS address (shorts) for [*][256] bf16 tile; conflict-free
// ds_read_b128 when 16 lanes read 16 consecutive rows at the same column.
DEV int zadr(int row, int col) {
    return row * 256 + ((((col >> 3) ^ (row & 7))) << 3) + (col & 7);
}

// ---------------- embed: z = x @ W_P + b_P + W_pos (all f32 in), bf16 out ----------------
// KEEP STANDALONE: 32768 blocks of trivially-parallel work -- fusing this into a
// tiled kernel (round-9 k_emq) trades away TLP and loses 2x.
__global__ void k_embed(const float* __restrict__ x,
                        const float* __restrict__ WP,
                        const float* __restrict__ bP,
                        const float* __restrict__ Wpos,
                        unsigned short* __restrict__ zb) {
    int row = blockIdx.x;            // b*Q + q
    int d   = threadIdx.x;           // 0..255
    int q   = row & (Qs - 1);
    const float* xr = x + row * 16;
    float acc = bP[d] + Wpos[q * Dm + d];
#pragma unroll
    for (int p = 0; p < 16; p++) acc += xr[p] * WP[p * Dm + d];
    zb[(long)row * Dm + d] = f2b(acc);
}

// ---------------- one-shot prep ----------------
// wTqkv: row-major [n][k] transpose (k_gemm layer-0 QKV).
// wpO/wpQ/wp1/wp2: FRAGMENT-MAJOR packs: for each 16(n) x 32(k) MFMA B-tile, the 64
// lanes' u16x8 fragments stored contiguously (512 shorts = 1KB/wave read).
// lane = quad*16+l16; n = ntile*16+(lane&15); k = kk*32+(lane>>4)*8+e.
static constexpr int S0a = 3 * 768 * 256;  // wTqkv [l][n(768)][k(256)], q-part scaled 0.25
static constexpr int S0b = 3 * 768 * 256;  // wpQ   fragment-major, ntile(48) x kk(8), q scaled
static constexpr int S1  = 3 * 256 * 256;  // wpO   fragment-major, ntile(16) x kk(8)
static constexpr int S2  = 3 * 512 * 256;  // wp1   fragment-major, ntile(32) x kk(8)
static constexpr int S3  = 3 * 256 * 512;  // wp2   fragment-major, ntile(16) x kslice(16)
static constexpr int S4  = 3 * 768;        // bqkv f32, q-part scaled 0.25
static constexpr int S5  = 3 * 64 * 256;   // pb: packed attn bias, [l][u(64)][tid(256)]
static constexpr int PREP_TOT = S0a + S0b + S1 + S2 + S3 + S4 + S5;

__global__ void k_prep(const float* __restrict__ Wq, const float* __restrict__ Wk,
                       const float* __restrict__ Wv, const float* __restrict__ Wo,
                       const float* __restrict__ W1, const float* __restrict__ W2,
                       const float* __restrict__ bq, const float* __restrict__ bk,
                       const float* __restrict__ bv, const float* __restrict__ ab,
                       unsigned short* __restrict__ wTqkv, unsigned short* __restrict__ wpQ,
                       unsigned short* __restrict__ wpO,
                       unsigned short* __restrict__ wp1, unsigned short* __restrict__ wp2,
                       float* __restrict__ bqkv, float* __restrict__ pb) {
    int idx = blockIdx.x * 256 + threadIdx.x;
    if (idx < S0a) {
        int l = idx / (768 * 256), r = idx % (768 * 256);
        int n = r / 256, k = r % 256;
        const float* W = (n < 256) ? Wq : (n < 512) ? Wk : Wv;
        float v = W[(long)l * 65536 + k * 256 + (n & 255)];
        if (n < 256) v *= 0.25f;            // fold DK^-0.5 into q
        wTqkv[idx] = f2b(v);
    } else if (idx < S0a + S0b) {
        int j = idx - S0a;
        int l = j / 196608, r = j % 196608;
        int tile = r >> 9, le = r & 511, lane = le >> 3, e = le & 7;
        int ntile = tile >> 3, kk = tile & 7;
        int n = ntile * 16 + (lane & 15), k = kk * 32 + (lane >> 4) * 8 + e;
        float v;
        if (n < 256)      v = Wq[(long)l * 65536 + k * 256 + n] * 0.25f;
        else if (n < 512) v = Wk[(long)l * 65536 + k * 256 + (n - 256)];
        else              v = Wv[(long)l * 65536 + k * 256 + (n - 512)];
        wpQ[j] = f2b(v);
    } else if (idx < S0a + S0b + S1) {
        int j = idx - S0a - S0b;
        int l = j / 65536, r = j % 65536;
        int tile = r >> 9, le = r & 511, lane = le >> 3, e = le & 7;
        int ntile = tile >> 3, kk = tile & 7;
        int n = ntile * 16 + (lane & 15), k = kk * 32 + (lane >> 4) * 8 + e;
        wpO[j] = f2b(Wo[(long)l * 65536 + k * 256 + n]);
    } else if (idx < S0a + S0b + S1 + S2) {
        int j = idx - S0a - S0b - S1;
        int l = j / 131072, r = j % 131072;
        int tile = r >> 9, le = r & 511, lane = le >> 3, e = le & 7;
        int ntile = tile >> 3, kk = tile & 7;
        int n = ntile * 16 + (lane & 15), k = kk * 32 + (lane >> 4) * 8 + e;
        wp1[j] = f2b(W1[(long)l * 131072 + k * 512 + n]);
    } else if (idx < S0a + S0b + S1 + S2 + S3) {
        int j = idx - S0a - S0b - S1 - S2;
        int l = j / 131072, r = j % 131072;
        int tile = r >> 9, le = r & 511, lane = le >> 3, e = le & 7;
        int ntile = tile >> 4, kk = tile & 15;              // K=512 -> 16 k-slices
        int n = ntile * 16 + (lane & 15), k = kk * 32 + (lane >> 4) * 8 + e;
        wp2[j] = f2b(W2[(long)l * 131072 + k * 256 + n]);
    } else if (idx < S0a + S0b + S1 + S2 + S3 + S4) {
        int j = idx - S0a - S0b - S1 - S2 - S3;
        int l = j / 768, c = j % 768;
        float v = (c < 256) ? bq[l * 256 + c] * 0.25f
                : (c < 512) ? bk[l * 256 + c - 256]
                            : bv[l * 256 + c - 512];
        bqkv[j] = v;
    } else if (idx < PREP_TOT) {
        int j = idx - S0a - S0b - S1 - S2 - S3 - S4;
        int l = j / 16384, r = j % 16384;
        int u = r / 256, t = r % 256;
        int i = u >> 5, rr = (u >> 3) & 3, jj = u & 7;
        int wave = t >> 6, quad = (t >> 4) & 3, l16 = t & 15;
        int m = 32 * wave + 16 * i + 4 * quad + rr;
        int col = 16 * jj + l16;
        pb[j] = (float)(l + 1) * ab[m * 128 + col];
    }
}

// ---------------- GEMM (layer-0 QKV): C = A @ W + bias, W as WT[NxK] bf16 ----------------
// 128x128 tile, 4 waves 2x2, two BK=32 sub-tiles per barrier; LDS-staged coalesced epilogue.
// MODE 2 = qkv split: col<512 -> head-major qk history, col>=512 -> v head-major [h][grow][dk]
template <int GELU, int MODE>
__global__ __launch_bounds__(256) void k_gemm(const unsigned short* __restrict__ A,
                                              const unsigned short* __restrict__ WT,
                                              const float* __restrict__ bias,
                                              unsigned short* __restrict__ outB,
                                              unsigned short* __restrict__ aux,
                                              int M, int N, int K) {
    __shared__ unsigned short smem[16384];     // As[2][4096] | Bs[2][4096]; C-stage after
    unsigned short* As = smem;
    unsigned short* Bs = smem + 8192;
    const int tid  = threadIdx.x;
    const int wave = tid >> 6, lane = tid & 63, quad = lane >> 4, l16 = lane & 15;
    const int mq = wave >> 1, nq = wave & 1;
    const int m_blk = blockIdx.x * 128, n_blk = blockIdx.y * 128;
    const int c0 = tid, c1 = tid + 256;
    const int ra0 = c0 >> 2, ca0 = (c0 & 3) * 8;
    const int ra1 = c1 >> 2, ca1 = (c1 & 3) * 8;

    f32x4 acc[4][4] = {};

    for (int k0 = 0; k0 < K; k0 += 64) {
#pragma unroll
        for (int hh = 0; hh < 2; hh++) {
            int kk = k0 + hh * 32;
            gl_lds16(A  + (long)(m_blk + ra0) * K + kk + ca0, &As[hh * 4096 + c0 * 8]);
            gl_lds16(A  + (long)(m_blk + ra1) * K + kk + ca1, &As[hh * 4096 + c1 * 8]);
            gl_lds16(WT + (long)(n_blk + ra0) * K + kk + ca0, &Bs[hh * 4096 + c0 * 8]);
            gl_lds16(WT + (long)(n_blk + ra1) * K + kk + ca1, &Bs[hh * 4096 + c1 * 8]);
        }
        __syncthreads();
#pragma unroll
        for (int hh = 0; hh < 2; hh++) {
            u16x8 af[4], bf[4];
#pragma unroll
            for (int i = 0; i < 4; i++)
                af[i] = *(const u16x8*)&As[hh * 4096 + (64 * mq + 16 * i + l16) * 32 + quad * 8];
#pragma unroll
            for (int j = 0; j < 4; j++)
                bf[j] = *(const u16x8*)&Bs[hh * 4096 + (64 * nq + 16 * j + l16) * 32 + quad * 8];
#pragma unroll
            for (int i = 0; i < 4; i++)
#pragma unroll
                for (int j = 0; j < 4; j++)
                    acc[i][j] = mfma_bf16(af[i], bf[j], acc[i][j]);
        }
        __syncthreads();
    }

#pragma unroll
    for (int i = 0; i < 4; i++) {
        int rl = 64 * mq + 16 * i + quad * 4;
#pragma unroll
        for (int j = 0; j < 4; j++) {
            int cl = 64 * nq + 16 * j + l16;
            float bb = bias[n_blk + cl];
#pragma unroll
            for (int r = 0; r < 4; r++) {
                float v = acc[i][j][r] + bb;
                if (GELU) v = 0.5f * v * (1.0f + erff(v * 0.70710678118f));
                if (MODE == 0) smem[(rl + r) * 128 + cl] = f2b(v);
                if (MODE == 2) {
                    int g = 4 * nq + j;                      // 16-col subtile within block
                    smem[g * 2048 + (rl + r) * 16 + l16] = f2b(v);
                }
            }
        }
    }
    __syncthreads();
#pragma unroll
    for (int c = tid; c < 2048; c += 256) {
        u16x8 val = *(const u16x8*)&smem[c * 8];
        if (MODE == 0) {
            int row = c >> 4, seg = c & 15;
            *(u16x8*)&outB[(long)(m_blk + row) * N + n_blk + seg * 8] = val;
        }
        if (MODE == 2) {
            int g = c >> 8, w = c & 255;                     // subtile, 16B-chunk within 4KB
            int n = n_blk + g * 16;
            if (n < 512) {
                int s = n >> 8, h = (n >> 4) & 15;
                *(u16x8*)&outB[((long)(((m_blk >> 7) * 16 + h) * 2 + s)) * 2048 + w * 8] = val;
            } else {
                int hh = (n - 512) >> 4;
                *(u16x8*)&aux[((long)hh * ROWS + m_blk) * 16 + w * 8] = val;
            }
        }
    }
}

// ---------------- Oproj + residual + LN1: zero-barrier frag-major, 32-row tiles ----------------
// z_b = LN1( z_b + o @ Wo + bo ).  1024 blocks x 256 thr (4 waves), 32KB LDS.
__global__ __launch_bounds__(256, 2) void k_oln(
    const unsigned short* __restrict__ zin,
    const unsigned short* __restrict__ ob,       // attn out, head-major [h][ROWS][16]
    const unsigned short* __restrict__ wpO, const float* __restrict__ bo,
    const float* __restrict__ g1, const float* __restrict__ be1,
    unsigned short* __restrict__ zout) {
    __shared__ unsigned short Zs[32 * 256];    // residual z (swizzled), 16 KB
    __shared__ unsigned short Os[32 * 256];    // o tile (swizzled), 16 KB; stats alias
    float2* stats = (float2*)Os;

    const int tid  = threadIdx.x;
    const int wave = tid >> 6, lane = tid & 63, quad = (lane >> 4) & 3, l16 = lane & 15;
    const int m_blk = blockIdx.x * 32;

    // ---- phase 0: stage z and o ----
#pragma unroll
    for (int s = 0; s < 4; s++) {
        int c = tid + 256 * s;
        int zr = c >> 5, zc = (c & 31) * 8;
        u16x8 vz = *(const u16x8*)&zin[(long)(m_blk + zr) * 256 + zc];
        *(u16x8*)&Zs[zadr(zr, zc)] = vz;
        int h = c >> 6, r = (c >> 1) & 31, hf = c & 1;
        u16x8 vo = *(const u16x8*)&ob[((long)h * ROWS + m_blk + r) * 16 + hf * 8];
        *(u16x8*)&Os[zadr(r, h * 16 + hf * 8)] = vo;
    }
    __syncthreads();

    // ---- phase 1: Oproj accO = o @ Wo (zero-barrier, B prefetched) ----
    f32x4 accO[2][4] = {};
    {
        u16x8 bf[2][4];
#pragma unroll
        for (int j = 0; j < 4; j++)
            bf[0][j] = *(const u16x8*)&wpO[((long)(4 * wave + j) * 8 + 0) * 512 + lane * 8];
#pragma unroll
        for (int kk = 0; kk < 8; kk++) {
            if (kk < 7)
#pragma unroll
                for (int j = 0; j < 4; j++)
                    bf[(kk + 1) & 1][j] = *(const u16x8*)&wpO[((long)(4 * wave + j) * 8 + kk + 1) * 512 + lane * 8];
            u16x8 af[2];
#pragma unroll
            for (int i = 0; i < 2; i++)
                af[i] = *(const u16x8*)&Os[(16 * i + l16) * 256 + (((kk * 4 + quad) ^ (l16 & 7)) << 3)];
#pragma unroll
            for (int i = 0; i < 2; i++)
#pragma unroll
                for (int j = 0; j < 4; j++)
                    accO[i][j] = mfma_bf16(af[i], bf[kk & 1][j], accO[i][j]);
        }
    }
    __syncthreads();   // Os reads done -> stats alias safe

    // ---- phase 2: residual + LN1 -> zout ----
    float bb[4], gg[4], bt[4];
#pragma unroll
    for (int j = 0; j < 4; j++) {
        int col = 64 * wave + 16 * j + l16;
        bb[j] = bo[col]; gg[j] = g1[col]; bt[j] = be1[col];
    }
#pragma unroll
    for (int i = 0; i < 2; i++)
#pragma unroll
        for (int r = 0; r < 4; r++) {
            int row = 16 * i + quad * 4 + r;
            float s1 = 0.f, s2 = 0.f;
#pragma unroll
            for (int j = 0; j < 4; j++) {
                int col = 64 * wave + 16 * j + l16;
                float v = accO[i][j][r] + bb[j] + b2f(Zs[zadr(row, col)]);
                accO[i][j][r] = v; s1 += v; s2 += v * v;
            }
            for (int mk = 1; mk < 16; mk <<= 1) { s1 += __shfl_xor(s1, mk); s2 += __shfl_xor(s2, mk); }
            if (l16 == 0) stats[row * 4 + wave] = make_float2(s1, s2);
        }
    __syncthreads();
#pragma unroll
    for (int i = 0; i < 2; i++)
#pragma unroll
        for (int r = 0; r < 4; r++) {
            int row = 16 * i + quad * 4 + r;
            f32x4 p0 = *(const f32x4*)&stats[row * 4];
            f32x4 p1 = *(const f32x4*)&stats[row * 4 + 2];
            float S1 = p0[0] + p0[2] + p1[0] + p1[2];
            float S2 = p0[1] + p0[3] + p1[1] + p1[3];
            float mean = S1 * (1.0f / 256.0f);
            float var  = S2 * (1.0f / 256.0f) - mean * mean;
            float rstd = rsqrtf(var + 1e-5f);
            long grow = m_blk + row;
#pragma unroll
            for (int j = 0; j < 4; j++) {
                int col = 64 * wave + 16 * j + l16;
                zout[grow * 256 + col] = f2b((accO[i][j][r] - mean) * rstd * gg[j] + bt[j]);
            }
        }
}

// ---------------- fused FFN (+ next-layer QKV tail): 32-row tiles, 32KB LDS ----------------
// z = LN2( z + gelu(z@W1+b1)@W2 + b2 ); then (non-LAST) QKV_{l+1} in 3 passes.
// 1024 blocks x 256 thr (4 waves). LDS shrunk 48->32KB via region overlap:
//   region A = smem[0:8192]    : z (GEMM1 input) -> h1 cols 256-511 -> post-LN2 z (QKV input)
//   region B = smem[8192:16384]: h1 cols 0-255 -> LN stats
// LN2 residual re-read from GLOBAL zin (L2-resident) since region A was overwritten.
// 32KB @ VGPR<=128 -> 4 blocks/CU; 1024 = 4x256 -> perfectly packed grid, no tail
// (round-11's 48KB/3-blk config averaged only 20% occupancy due to the 256-block tail).
// Phases strictly sequential (round-7 recipe); per-phase live set ~72 regs -> no spill.
template <int LAST>
__global__ __launch_bounds__(256, 2) void k_ffn(
    const unsigned short* __restrict__ zin,      // post-LN1 z
    const unsigned short* __restrict__ wp1, const float* __restrict__ b1,
    const unsigned short* __restrict__ wp2, const float* __restrict__ b2,
    const float* __restrict__ g2, const float* __restrict__ be2,
    unsigned short* __restrict__ zout, float* __restrict__ outF,
    const unsigned short* __restrict__ wpQ, const float* __restrict__ bqn,
    unsigned short* __restrict__ qkhn, unsigned short* __restrict__ vcurn) {
    __shared__ unsigned short smem[16384];     // 32 KB
    float2* stats = (float2*)(smem + 8192);    // region B alias (valid after GEMM2)

    const int tid  = threadIdx.x;
    const int wave = tid >> 6, lane = tid & 63, quad = (lane >> 4) & 3, l16 = lane & 15;
    const int m_blk = blockIdx.x * 32;

    // ---- phase 0: stage z -> region A (swizzled) ----
#pragma unroll
    for (int s = 0; s < 4; s++) {
        int c = tid + 256 * s;
        int zr = c >> 5, zc = (c & 31) * 8;
        u16x8 v = *(const u16x8*)&zin[(long)(m_blk + zr) * 256 + zc];
        *(u16x8*)&smem[zadr(zr, zc)] = v;
    }
    __syncthreads();

    // ---- phase 1: GEMM1, two 256-col passes; gelu(pass 0) -> region B,
    //      gelu(pass 1) -> region A (after barrier: all z reads complete) ----
#pragma unroll 1
    for (int p = 0; p < 2; p++) {
        f32x4 a1[2][4] = {};
        u16x8 bf[2][4];
#pragma unroll
        for (int j = 0; j < 4; j++)
            bf[0][j] = *(const u16x8*)&wp1[((long)(16 * p + 4 * wave + j) * 8 + 0) * 512 + lane * 8];
#pragma unroll
        for (int kk = 0; kk < 8; kk++) {
            if (kk < 7)
#pragma unroll
                for (int j = 0; j < 4; j++)
                    bf[(kk + 1) & 1][j] = *(const u16x8*)&wp1[((long)(16 * p + 4 * wave + j) * 8 + kk + 1) * 512 + lane * 8];
            u16x8 af[2];
#pragma unroll
            for (int i = 0; i < 2; i++)
                af[i] = *(const u16x8*)&smem[(16 * i + l16) * 256 + (((kk * 4 + quad) ^ (l16 & 7)) << 3)];
#pragma unroll
            for (int i = 0; i < 2; i++)
#pragma unroll
                for (int j = 0; j < 4; j++)
                    a1[i][j] = mfma_bf16(af[i], bf[kk & 1][j], a1[i][j]);
        }
        if (p == 1) __syncthreads();   // all waves' z reads done before overwriting region A
        float b1v[4];
#pragma unroll
        for (int j = 0; j < 4; j++) b1v[j] = b1[256 * p + 64 * wave + 16 * j + l16];
        const int hbase = (p == 0) ? 8192 : 0;
#pragma unroll
        for (int i = 0; i < 2; i++)
#pragma unroll
            for (int j = 0; j < 4; j++)
#pragma unroll
                for (int r = 0; r < 4; r++) {
                    int row  = 16 * i + quad * 4 + r;
                    int colh = 64 * wave + 16 * j + l16;      // within-pass col
                    float v = a1[i][j][r] + b1v[j];
                    float gel = 0.5f * v * (1.0f + erff(v * 0.70710678118f));
                    smem[hbase + zadr(row, colh)] = f2b(gel);
                }
    }
    __syncthreads();   // full h1 visible (B: cols 0-255, A: cols 256-511)

    // ---- phase 2: GEMM2, K=512 single zero-barrier loop ----
    f32x4 z2[2][4] = {};
    {
        u16x8 bg[2][4];
#pragma unroll
        for (int j = 0; j < 4; j++)
            bg[0][j] = *(const u16x8*)&wp2[((long)(4 * wave + j) * 16 + 0) * 512 + lane * 8];
#pragma unroll
        for (int kk = 0; kk < 16; kk++) {
            if (kk < 15)
#pragma unroll
                for (int j = 0; j < 4; j++)
                    bg[(kk + 1) & 1][j] = *(const u16x8*)&wp2[((long)(4 * wave + j) * 16 + kk + 1) * 512 + lane * 8];
            u16x8 af[2];
            const int hb = (kk < 8) ? 8192 : 0;               // h1 col = kk*32+... region
#pragma unroll
            for (int i = 0; i < 2; i++)
                af[i] = *(const u16x8*)&smem[hb + (16 * i + l16) * 256 + (((((kk * 4 + quad) & 31)) ^ (l16 & 7)) << 3)];
#pragma unroll
            for (int i = 0; i < 2; i++)
#pragma unroll
                for (int j = 0; j < 4; j++)
                    z2[i][j] = mfma_bf16(af[i], bg[kk & 1][j], z2[i][j]);
        }
    }
    __syncthreads();   // h1 reads done -> stats alias + region A reuse safe

    // ---- phase 3: residual (global re-read) + LN2 ----
    float b2v[4], gg[4], bb[4];
#pragma unroll
    for (int j = 0; j < 4; j++) {
        int col = 64 * wave + 16 * j + l16;
        b2v[j] = b2[col]; gg[j] = g2[col]; bb[j] = be2[col];
    }
#pragma unroll
    for (int i = 0; i < 2; i++)
#pragma unroll
        for (int r = 0; r < 4; r++) {
            int row = 16 * i + quad * 4 + r;
            float s1 = 0.f, s2 = 0.f;
#pragma unroll
            for (int j = 0; j < 4; j++) {
                int col = 64 * wave + 16 * j + l16;
                float v = z2[i][j][r] + b2v[j] + b2f(zin[(long)(m_blk + row) * 256 + col]);
                z2[i][j][r] = v; s1 += v; s2 += v * v;
            }
            for (int mk = 1; mk < 16; mk <<= 1) { s1 += __shfl_xor(s1, mk); s2 += __shfl_xor(s2, mk); }
            if (l16 == 0) stats[row * 4 + wave] = make_float2(s1, s2);
        }
    __syncthreads();
#pragma unroll
    for (int i = 0; i < 2; i++)
#pragma unroll
        for (int r = 0; r < 4; r++) {
            int row = 16 * i + quad * 4 + r;
            f32x4 p0 = *(const f32x4*)&stats[row * 4];
            f32x4 p1 = *(const f32x4*)&stats[row * 4 + 2];
            float S1 = p0[0] + p0[2] + p1[0] + p1[2];
            float S2 = p0[1] + p0[3] + p1[1] + p1[3];
            float mean = S1 * (1.0f / 256.0f);
            float var  = S2 * (1.0f / 256.0f) - mean * mean;
            float rstd = rsqrtf(var + 1e-5f);
            long grow = m_blk + row;
#pragma unroll
            for (int j = 0; j < 4; j++) {
                int col = 64 * wave + 16 * j + l16;
                float o = (z2[i][j][r] - mean) * rstd * gg[j] + bb[j];
                if constexpr (LAST) {
                    outF[grow * 256 + col] = o;
                } else {
                    unsigned short hv = f2b(o);
                    smem[zadr(row, col)] = hv;      // post-LN2 z -> region A for QKV
                    zout[grow * 256 + col] = hv;
                }
            }
        }

    if constexpr (!LAST) {
        __syncthreads();   // region A now holds post-LN2 z
        // ---- phase 4: QKV_{l+1}, 3 passes of 256 cols (p=0: q, p=1: k, p=2: v) ----
        const int bb_ = m_blk >> 7;               // batch
        const int rbase = m_blk & 127;            // row offset within batch
#pragma unroll 1
        for (int p = 0; p < 3; p++) {
            f32x4 aq[2][4] = {};
            {
                u16x8 bf[2][4];
#pragma unroll
                for (int j = 0; j < 4; j++)
                    bf[0][j] = *(const u16x8*)&wpQ[((long)(16 * p + 4 * wave + j) * 8 + 0) * 512 + lane * 8];
#pragma unroll
                for (int kk = 0; kk < 8; kk++) {
                    if (kk < 7)
#pragma unroll
                        for (int j = 0; j < 4; j++)
                            bf[(kk + 1) & 1][j] = *(const u16x8*)&wpQ[((long)(16 * p + 4 * wave + j) * 8 + kk + 1) * 512 + lane * 8];
                    u16x8 af[2];
#pragma unroll
                    for (int i = 0; i < 2; i++)
                        af[i] = *(const u16x8*)&smem[(16 * i + l16) * 256 + (((kk * 4 + quad) ^ (l16 & 7)) << 3)];
#pragma unroll
                    for (int i = 0; i < 2; i++)
#pragma unroll
                        for (int j = 0; j < 4; j++)
                            aq[i][j] = mfma_bf16(af[i], bf[kk & 1][j], aq[i][j]);
                }
            }
            // epilogue: q/k -> head-major qk history; v -> head-major [h][row][dk]
#pragma unroll
            for (int j = 0; j < 4; j++) {
                int col = 256 * p + 64 * wave + 16 * j + l16;
                float bqv = bqn[col];
                int h = 4 * wave + j;                         // head (uniform per wave,j)
                if (p < 2) {
                    unsigned short* qk = qkhn + ((long)((bb_ * 16 + h) * 2 + p)) * 2048;
#pragma unroll
                    for (int i = 0; i < 2; i++)
#pragma unroll
                        for (int r = 0; r < 4; r++) {
                            int rin = rbase + 16 * i + quad * 4 + r;
                            qk[rin * 16 + l16] = f2b(aq[i][j][r] + bqv);
                        }
                } else {
#pragma unroll
                    for (int i = 0; i < 2; i++)
#pragma unroll
                        for (int r = 0; r < 4; r++) {
                            long grow = m_blk + 16 * i + quad * 4 + r;
                            vcurn[((long)h * ROWS + grow) * 16 + l16] = f2b(aq[i][j][r] + bqv);
                        }
                }
            }
        }
    }
}

// ---------------- fused attention for layer L (score-carry recompute) ----------------
template <int L>
__global__ __launch_bounds__(256) void k_attn(const unsigned short* __restrict__ qkh,
                                              const unsigned short* __restrict__ vbuf,
                                              const float* __restrict__ pb,
                                              unsigned short* __restrict__ o_out) {
    __shared__ unsigned short vt[16 * 136];   // v^T [dk][key]; reused to stage o
    __shared__ unsigned short Ps[128 * 136];  // unnormalized probs, ld 136
    const int tid  = threadIdx.x;
    const int wave = tid >> 6, lane = tid & 63, quad = lane >> 4, l16 = lane & 15;
    const int b = blockIdx.x >> 4, h = blockIdx.x & 15;
    const int qrow = tid >> 1, half = tid & 1;

    u16x8 vv = *(const u16x8*)(vbuf + ((long)h * ROWS + b * Qs + qrow) * 16 + half * 8);
    const float* pbt = pb + (long)L * 16384 + tid;

    f32x4 accS[2][8] = {};
    u16x8 zero = {};

    constexpr int FULL = (L + 1) / 2;
    constexpr bool HALF = ((L + 1) & 1) != 0;

#pragma unroll
    for (int p = 0; p < FULL; p++) {
        const unsigned short* q0 = qkh + ((long)(((2 * p) * Bq + b) * 16 + h) * 2) * 2048;
        const unsigned short* q1 = qkh + ((long)(((2 * p + 1) * Bq + b) * 16 + h) * 2) * 2048;
        const unsigned short* qsel = (quad < 2) ? q0 : q1;
        const unsigned short* ksel = (quad < 2) ? (q0 + 2048) : (q1 + 2048);
        const int koff = (quad & 1) * 8;
        u16x8 af[2], bf8[8];
#pragma unroll
        for (int i = 0; i < 2; i++) {
            int m = 32 * wave + 16 * i + l16;
            af[i] = *(const u16x8*)(qsel + m * 16 + koff);
        }
#pragma unroll
        for (int j = 0; j < 8; j++) {
            int n = 16 * j + l16;
            bf8[j] = *(const u16x8*)(ksel + n * 16 + koff);
        }
#pragma unroll
        for (int i = 0; i < 2; i++)
#pragma unroll
            for (int j = 0; j < 8; j++)
                accS[i][j] = mfma_bf16(af[i], bf8[j], accS[i][j]);
    }
    if (HALF) {
        const unsigned short* qt = qkh + ((long)((L * Bq + b) * 16 + h) * 2) * 2048;
        const unsigned short* kt = qt + 2048;
        u16x8 af[2], bf8[8];
#pragma unroll
        for (int i = 0; i < 2; i++) {
            int m = 32 * wave + 16 * i + l16;
            af[i] = (quad < 2) ? *(const u16x8*)(qt + m * 16 + quad * 8) : zero;
        }
#pragma unroll
        for (int j = 0; j < 8; j++) {
            int n = 16 * j + l16;
            bf8[j] = (quad < 2) ? *(const u16x8*)(kt + n * 16 + quad * 8) : zero;
        }
#pragma unroll
        for (int i = 0; i < 2; i++)
#pragma unroll
            for (int j = 0; j < 8; j++)
                accS[i][j] = mfma_bf16(af[i], bf8[j], accS[i][j]);
    }

#pragma unroll
    for (int jj = 0; jj < 8; jj++) vt[(half * 8 + jj) * 136 + qrow] = vv[jj];

#pragma unroll
    for (int i = 0; i < 2; i++) {
#pragma unroll
        for (int r = 0; r < 4; r++) {
            int m = 32 * wave + 16 * i + quad * 4 + r;
#pragma unroll
            for (int j = 0; j < 8; j++) {
                int u = (i * 4 + r) * 8 + j;
                float s = accS[i][j][r] + pbt[u * 256];
                Ps[m * 136 + 16 * j + l16] = f2b(__expf(s));
            }
        }
    }
    __syncthreads();

    f32x4 accO[2] = {};
    f32x4 accR[2] = {};
    u16x8 ones;
#pragma unroll
    for (int jj = 0; jj < 8; jj++) ones[jj] = 0x3F80;
#pragma unroll
    for (int s = 0; s < 4; s++) {
        u16x8 bv = *(const u16x8*)&vt[l16 * 136 + s * 32 + quad * 8];
#pragma unroll
        for (int i = 0; i < 2; i++) {
            u16x8 ap = *(const u16x8*)&Ps[(32 * wave + 16 * i + l16) * 136 + s * 32 + quad * 8];
            accO[i] = mfma_bf16(ap, bv, accO[i]);
            accR[i] = mfma_bf16(ap, ones, accR[i]);
        }
    }
    __syncthreads();
#pragma unroll
    for (int i = 0; i < 2; i++)
#pragma unroll
        for (int r = 0; r < 4; r++) {
            int m = 32 * wave + 16 * i + quad * 4 + r;
            float inv = __builtin_amdgcn_rcpf(accR[i][r]);
            vt[m * 16 + l16] = f2b(accO[i][r] * inv);
        }
    __syncthreads();
    {
        unsigned short* obase = o_out + ((long)h * ROWS + b * Qs) * 16;
        *(u16x8*)&obase[tid * 8] = *(const u16x8*)&vt[tid * 8];
    }
}

extern "C" void kernel_launch(void* const* d_in, const int* in_sizes, int n_in,
                              void* d_out, int out_size, void* d_ws, size_t ws_size,
                              hipStream_t stream) {
    const float* x     = (const float*)d_in[0];
    const float* abias = (const float*)d_in[1];
    const float* WP    = (const float*)d_in[2];
    const float* bP    = (const float*)d_in[3];
    const float* Wpos  = (const float*)d_in[4];
    const float* Wq    = (const float*)d_in[5];
    const float* bqp   = (const float*)d_in[6];
    const float* Wk    = (const float*)d_in[7];
    const float* bkp   = (const float*)d_in[8];
    const float* Wv    = (const float*)d_in[9];
    const float* bvp   = (const float*)d_in[10];
    const float* Wo    = (const float*)d_in[11];
    const float* bo    = (const float*)d_in[12];
    const float* g1    = (const float*)d_in[13];
    const float* be1   = (const float*)d_in[14];
    const float* W1    = (const float*)d_in[15];
    const float* b1    = (const float*)d_in[16];
    const float* W2    = (const float*)d_in[17];
    const float* b2    = (const float*)d_in[18];
    const float* g2    = (const float*)d_in[19];
    const float* be2   = (const float*)d_in[20];
    (void)in_sizes; (void)n_in; (void)out_size; (void)ws_size;

    char* ws = (char*)d_ws;
    size_t off = 0;
    auto alloc = [&](size_t bytes) -> char* {
        char* p = ws + off; off += (bytes + 255) & ~(size_t)255; return p;
    };
    unsigned short* z_b   = (unsigned short*)alloc((size_t)ROWS * Dm * 2);      // 16.8 MB
    unsigned short* qkh   = (unsigned short*)alloc((size_t)3 * ROWS * 512 * 2); // 100.7 MB head-major
    unsigned short* v_cur = (unsigned short*)alloc((size_t)ROWS * Dm * 2);      // 16.8 MB head-major
    unsigned short* o_b   = (unsigned short*)alloc((size_t)ROWS * Dm * 2);      // 16.8 MB head-major
    unsigned short* wTqkv = (unsigned short*)alloc((size_t)S0a * 2);
    unsigned short* wpQ   = (unsigned short*)alloc((size_t)S0b * 2);
    unsigned short* wpO   = (unsigned short*)alloc((size_t)S1 * 2);
    unsigned short* wp1   = (unsigned short*)alloc((size_t)S2 * 2);
    unsigned short* wp2   = (unsigned short*)alloc((size_t)S3 * 2);
    float*          bqkv  = (float*)alloc((size_t)S4 * 4);
    float*          pb    = (float*)alloc((size_t)S5 * 4);

    k_prep<<<(PREP_TOT + 255) / 256, 256, 0, stream>>>(
        Wq, Wk, Wv, Wo, W1, W2, bqp, bkp, bvp, abias,
        wTqkv, wpQ, wpO, wp1, wp2, bqkv, pb);
    k_embed<<<ROWS, 256, 0, stream>>>(x, WP, bP, Wpos, z_b);

    // layer-0 QKV on the proven 2-barrier GEMM
    k_gemm<0, 2><<<dim3(ROWS / 128, 6), 256, 0, stream>>>(
        z_b, wTqkv, bqkv, qkh, v_cur, ROWS, 768, 256);

    for (int l = 0; l < 3; l++) {
        // attention with score-carry recompute (layer-packed K)
        if (l == 0)      k_attn<0><<<Bq * 16, 256, 0, stream>>>(qkh, v_cur, pb, o_b);
        else if (l == 1) k_attn<1><<<Bq * 16, 256, 0, stream>>>(qkh, v_cur, pb, o_b);
        else             k_attn<2><<<Bq * 16, 256, 0, stream>>>(qkh, v_cur, pb, o_b);
        // O projection + residual + LN1: zero-barrier frag-major
        k_oln<<<ROWS / 32, 256, 0, stream>>>(
            z_b, o_b, wpO + (long)l * 65536, bo + l * 256,
            g1 + l * 256, be1 + l * 256, z_b);
        // fused FFN + LN2 (+ next-layer QKV tail); last layer writes f32 d_out
        if (l < 2)
            k_ffn<0><<<ROWS / 32, 256, 0, stream>>>(
                z_b, wp1 + (long)l * 131072, b1 + l * 512,
                wp2 + (long)l * 131072, b2 + l * 256,
                g2 + l * 256, be2 + l * 256, z_b, nullptr,
                wpQ + (long)(l + 1) * 196608, bqkv + (l + 1) * 768,
                qkh + (long)(l + 1) * QK_LSTR, v_cur);
        else
            k_ffn<1><<<ROWS / 32, 256, 0, stream>>>(
                z_b, wp1 + (long)l * 131072, b1 + l * 512,
                wp2 + (long)l * 131072, b2 + l * 256,
                g2 + l * 256, be2 + l * 256, nullptr, (float*)d_out,
                nullptr, nullptr, nullptr, nullptr);
    }
}

// Round 13
// 483.964 us; speedup vs baseline: 1.0106x; 1.0106x over previous
//
#include <hip/hip_runtime.h>

#define DEV __device__ __forceinline__

typedef float          f32x4  __attribute__((ext_vector_type(4)));
typedef __bf16         bf16x8 __attribute__((ext_vector_type(8)));
typedef unsigned short u16x8  __attribute__((ext_vector_type(8)));

static constexpr int  Bq   = 256;   // batch
static constexpr int  Qs   = 128;   // seq len
static constexpr int  Dm   = 256;   // model dim
static constexpr int  Ff   = 512;   // ffn dim
static constexpr int  ROWS = Bq * Qs;               // 32768
static constexpr long QK_LSTR = (long)ROWS * 512;   // q||k history per layer (head-major)

DEV float b2f(unsigned short h) {
    unsigned int u = ((unsigned int)h) << 16;
    float f; __builtin_memcpy(&f, &u, 4); return f;
}
DEV unsigned short f2b(float f) {
    unsigned int u; __builtin_memcpy(&u, &f, 4);
    u += 0x7fffu + ((u >> 16) & 1u);   // RNE
    return (unsigned short)(u >> 16);
}
DEV f32x4 mfma_bf16(u16x8 a, u16x8 b, f32x4 c) {
    return __builtin_amdgcn_mfma_f32_16x16x32_bf16(
        __builtin_bit_cast(bf16x8, a), __builtin_bit_cast(bf16x8, b), c, 0, 0, 0);
}
// async global->LDS, 16B per lane; LDS dst must be wave-uniform base + lane*16
DEV void gl_lds16(const unsigned short* g, unsigned short* l) {
    __builtin_amdgcn_global_load_lds(
        (const __attribute__((address_space(1))) unsigned int*)g,
        (__attribute__((address_space(3))) unsigned int*)l, 16, 0, 0);
}
// XOR-chunk-swizzled LDS address (shorts) for [*][256] bf16 tile; conflict-free
// ds_read_b128 when 16 lanes read 16 consecutive rows at the same column.
DEV int zadr(int row, int col) {
    return row * 256 + ((((col >> 3) ^ (row & 7))) << 3) + (col & 7);
}
// same for [*][512] tiles
DEV int hadr(int row, int col) {
    return row * 512 + ((((col >> 3) ^ (row & 7))) << 3) + (col & 7);
}

// ---------------- embed: z = x @ W_P + b_P + W_pos (all f32 in), bf16 out ----------------
// KEEP STANDALONE: 32768 blocks of trivially-parallel work (round-9 lesson).
__global__ void k_embed(const float* __restrict__ x,
                        const float* __restrict__ WP,
                        const float* __restrict__ bP,
                        const float* __restrict__ Wpos,
                        unsigned short* __restrict__ zb) {
    int row = blockIdx.x;            // b*Q + q
    int d   = threadIdx.x;           // 0..255
    int q   = row & (Qs - 1);
    const float* xr = x + row * 16;
    float acc = bP[d] + Wpos[q * Dm + d];
#pragma unroll
    for (int p = 0; p < 16; p++) acc += xr[p] * WP[p * Dm + d];
    zb[(long)row * Dm + d] = f2b(acc);
}

// ---------------- one-shot prep ----------------
static constexpr int S0a = 3 * 768 * 256;  // wTqkv [l][n(768)][k(256)], q-part scaled 0.25
static constexpr int S0b = 3 * 768 * 256;  // wpQ   fragment-major, ntile(48) x kk(8), q scaled
static constexpr int S1  = 3 * 256 * 256;  // wpO   fragment-major, ntile(16) x kk(8)
static constexpr int S2  = 3 * 512 * 256;  // wp1   fragment-major, ntile(32) x kk(8)
static constexpr int S3  = 3 * 256 * 512;  // wp2   fragment-major, ntile(16) x kslice(16)
static constexpr int S4  = 3 * 768;        // bqkv f32, q-part scaled 0.25
static constexpr int S5  = 3 * 64 * 256;   // pb: packed attn bias, [l][u(64)][tid(256)]
static constexpr int PREP_TOT = S0a + S0b + S1 + S2 + S3 + S4 + S5;

__global__ void k_prep(const float* __restrict__ Wq, const float* __restrict__ Wk,
                       const float* __restrict__ Wv, const float* __restrict__ Wo,
                       const float* __restrict__ W1, const float* __restrict__ W2,
                       const float* __restrict__ bq, const float* __restrict__ bk,
                       const float* __restrict__ bv, const float* __restrict__ ab,
                       unsigned short* __restrict__ wTqkv, unsigned short* __restrict__ wpQ,
                       unsigned short* __restrict__ wpO,
                       unsigned short* __restrict__ wp1, unsigned short* __restrict__ wp2,
                       float* __restrict__ bqkv, float* __restrict__ pb) {
    int idx = blockIdx.x * 256 + threadIdx.x;
    if (idx < S0a) {
        int l = idx / (768 * 256), r = idx % (768 * 256);
        int n = r / 256, k = r % 256;
        const float* W = (n < 256) ? Wq : (n < 512) ? Wk : Wv;
        float v = W[(long)l * 65536 + k * 256 + (n & 255)];
        if (n < 256) v *= 0.25f;            // fold DK^-0.5 into q
        wTqkv[idx] = f2b(v);
    } else if (idx < S0a + S0b) {
        int j = idx - S0a;
        int l = j / 196608, r = j % 196608;
        int tile = r >> 9, le = r & 511, lane = le >> 3, e = le & 7;
        int ntile = tile >> 3, kk = tile & 7;
        int n = ntile * 16 + (lane & 15), k = kk * 32 + (lane >> 4) * 8 + e;
        float v;
        if (n < 256)      v = Wq[(long)l * 65536 + k * 256 + n] * 0.25f;
        else if (n < 512) v = Wk[(long)l * 65536 + k * 256 + (n - 256)];
        else              v = Wv[(long)l * 65536 + k * 256 + (n - 512)];
        wpQ[j] = f2b(v);
    } else if (idx < S0a + S0b + S1) {
        int j = idx - S0a - S0b;
        int l = j / 65536, r = j % 65536;
        int tile = r >> 9, le = r & 511, lane = le >> 3, e = le & 7;
        int ntile = tile >> 3, kk = tile & 7;
        int n = ntile * 16 + (lane & 15), k = kk * 32 + (lane >> 4) * 8 + e;
        wpO[j] = f2b(Wo[(long)l * 65536 + k * 256 + n]);
    } else if (idx < S0a + S0b + S1 + S2) {
        int j = idx - S0a - S0b - S1;
        int l = j / 131072, r = j % 131072;
        int tile = r >> 9, le = r & 511, lane = le >> 3, e = le & 7;
        int ntile = tile >> 3, kk = tile & 7;
        int n = ntile * 16 + (lane & 15), k = kk * 32 + (lane >> 4) * 8 + e;
        wp1[j] = f2b(W1[(long)l * 131072 + k * 512 + n]);
    } else if (idx < S0a + S0b + S1 + S2 + S3) {
        int j = idx - S0a - S0b - S1 - S2;
        int l = j / 131072, r = j % 131072;
        int tile = r >> 9, le = r & 511, lane = le >> 3, e = le & 7;
        int ntile = tile >> 4, kk = tile & 15;              // K=512 -> 16 k-slices
        int n = ntile * 16 + (lane & 15), k = kk * 32 + (lane >> 4) * 8 + e;
        wp2[j] = f2b(W2[(long)l * 131072 + k * 256 + n]);
    } else if (idx < S0a + S0b + S1 + S2 + S3 + S4) {
        int j = idx - S0a - S0b - S1 - S2 - S3;
        int l = j / 768, c = j % 768;
        float v = (c < 256) ? bq[l * 256 + c] * 0.25f
                : (c < 512) ? bk[l * 256 + c - 256]
                            : bv[l * 256 + c - 512];
        bqkv[j] = v;
    } else if (idx < PREP_TOT) {
        int j = idx - S0a - S0b - S1 - S2 - S3 - S4;
        int l = j / 16384, r = j % 16384;
        int u = r / 256, t = r % 256;
        int i = u >> 5, rr = (u >> 3) & 3, jj = u & 7;
        int wave = t >> 6, quad = (t >> 4) & 3, l16 = t & 15;
        int m = 32 * wave + 16 * i + 4 * quad + rr;
        int col = 16 * jj + l16;
        pb[j] = (float)(l + 1) * ab[m * 128 + col];
    }
}

// ---------------- GEMM (layer-0 QKV): C = A @ W + bias, W as WT[NxK] bf16 ----------------
template <int GELU, int MODE>
__global__ __launch_bounds__(256) void k_gemm(const unsigned short* __restrict__ A,
                                              const unsigned short* __restrict__ WT,
                                              const float* __restrict__ bias,
                                              unsigned short* __restrict__ outB,
                                              unsigned short* __restrict__ aux,
                                              int M, int N, int K) {
    __shared__ unsigned short smem[16384];     // As[2][4096] | Bs[2][4096]; C-stage after
    unsigned short* As = smem;
    unsigned short* Bs = smem + 8192;
    const int tid  = threadIdx.x;
    const int wave = tid >> 6, lane = tid & 63, quad = lane >> 4, l16 = lane & 15;
    const int mq = wave >> 1, nq = wave & 1;
    const int m_blk = blockIdx.x * 128, n_blk = blockIdx.y * 128;
    const int c0 = tid, c1 = tid + 256;
    const int ra0 = c0 >> 2, ca0 = (c0 & 3) * 8;
    const int ra1 = c1 >> 2, ca1 = (c1 & 3) * 8;

    f32x4 acc[4][4] = {};

    for (int k0 = 0; k0 < K; k0 += 64) {
#pragma unroll
        for (int hh = 0; hh < 2; hh++) {
            int kk = k0 + hh * 32;
            gl_lds16(A  + (long)(m_blk + ra0) * K + kk + ca0, &As[hh * 4096 + c0 * 8]);
            gl_lds16(A  + (long)(m_blk + ra1) * K + kk + ca1, &As[hh * 4096 + c1 * 8]);
            gl_lds16(WT + (long)(n_blk + ra0) * K + kk + ca0, &Bs[hh * 4096 + c0 * 8]);
            gl_lds16(WT + (long)(n_blk + ra1) * K + kk + ca1, &Bs[hh * 4096 + c1 * 8]);
        }
        __syncthreads();
#pragma unroll
        for (int hh = 0; hh < 2; hh++) {
            u16x8 af[4], bf[4];
#pragma unroll
            for (int i = 0; i < 4; i++)
                af[i] = *(const u16x8*)&As[hh * 4096 + (64 * mq + 16 * i + l16) * 32 + quad * 8];
#pragma unroll
            for (int j = 0; j < 4; j++)
                bf[j] = *(const u16x8*)&Bs[hh * 4096 + (64 * nq + 16 * j + l16) * 32 + quad * 8];
#pragma unroll
            for (int i = 0; i < 4; i++)
#pragma unroll
                for (int j = 0; j < 4; j++)
                    acc[i][j] = mfma_bf16(af[i], bf[j], acc[i][j]);
        }
        __syncthreads();
    }

#pragma unroll
    for (int i = 0; i < 4; i++) {
        int rl = 64 * mq + 16 * i + quad * 4;
#pragma unroll
        for (int j = 0; j < 4; j++) {
            int cl = 64 * nq + 16 * j + l16;
            float bb = bias[n_blk + cl];
#pragma unroll
            for (int r = 0; r < 4; r++) {
                float v = acc[i][j][r] + bb;
                if (GELU) v = 0.5f * v * (1.0f + erff(v * 0.70710678118f));
                if (MODE == 0) smem[(rl + r) * 128 + cl] = f2b(v);
                if (MODE == 2) {
                    int g = 4 * nq + j;                      // 16-col subtile within block
                    smem[g * 2048 + (rl + r) * 16 + l16] = f2b(v);
                }
            }
        }
    }
    __syncthreads();
#pragma unroll
    for (int c = tid; c < 2048; c += 256) {
        u16x8 val = *(const u16x8*)&smem[c * 8];
        if (MODE == 0) {
            int row = c >> 4, seg = c & 15;
            *(u16x8*)&outB[(long)(m_blk + row) * N + n_blk + seg * 8] = val;
        }
        if (MODE == 2) {
            int g = c >> 8, w = c & 255;                     // subtile, 16B-chunk within 4KB
            int n = n_blk + g * 16;
            if (n < 512) {
                int s = n >> 8, h = (n >> 4) & 15;
                *(u16x8*)&outB[((long)(((m_blk >> 7) * 16 + h) * 2 + s)) * 2048 + w * 8] = val;
            } else {
                int hh = (n - 512) >> 4;
                *(u16x8*)&aux[((long)hh * ROWS + m_blk) * 16 + w * 8] = val;
            }
        }
    }
}

// ---------------- Oproj + residual + LN1: zero-barrier frag-major, 32-row tiles ----------------
// z_b = LN1( z_b + o @ Wo + bo ).  1024 blocks x 256 thr (4 waves), 32KB LDS.
// Ring-3 B prefetch (distance 2) to cover L2 latency (round-13 change).
__global__ __launch_bounds__(256, 2) void k_oln(
    const unsigned short* __restrict__ zin,
    const unsigned short* __restrict__ ob,       // attn out, head-major [h][ROWS][16]
    const unsigned short* __restrict__ wpO, const float* __restrict__ bo,
    const float* __restrict__ g1, const float* __restrict__ be1,
    unsigned short* __restrict__ zout) {
    __shared__ unsigned short Zs[32 * 256];    // residual z (swizzled), 16 KB
    __shared__ unsigned short Os[32 * 256];    // o tile (swizzled), 16 KB; stats alias
    float2* stats = (float2*)Os;

    const int tid  = threadIdx.x;
    const int wave = tid >> 6, lane = tid & 63, quad = (lane >> 4) & 3, l16 = lane & 15;
    const int m_blk = blockIdx.x * 32;

    // ---- phase 0: stage z and o ----
#pragma unroll
    for (int s = 0; s < 4; s++) {
        int c = tid + 256 * s;
        int zr = c >> 5, zc = (c & 31) * 8;
        u16x8 vz = *(const u16x8*)&zin[(long)(m_blk + zr) * 256 + zc];
        *(u16x8*)&Zs[zadr(zr, zc)] = vz;
        int h = c >> 6, r = (c >> 1) & 31, hf = c & 1;
        u16x8 vo = *(const u16x8*)&ob[((long)h * ROWS + m_blk + r) * 16 + hf * 8];
        *(u16x8*)&Os[zadr(r, h * 16 + hf * 8)] = vo;
    }
    __syncthreads();

    // ---- phase 1: Oproj accO = o @ Wo (zero-barrier, ring-3 B prefetch) ----
    f32x4 accO[2][4] = {};
    {
        u16x8 bf[3][4];
#pragma unroll
        for (int j = 0; j < 4; j++) {
            bf[0][j] = *(const u16x8*)&wpO[((long)(4 * wave + j) * 8 + 0) * 512 + lane * 8];
            bf[1][j] = *(const u16x8*)&wpO[((long)(4 * wave + j) * 8 + 1) * 512 + lane * 8];
        }
#pragma unroll
        for (int kk = 0; kk < 8; kk++) {
            if (kk < 6)
#pragma unroll
                for (int j = 0; j < 4; j++)
                    bf[(kk + 2) % 3][j] = *(const u16x8*)&wpO[((long)(4 * wave + j) * 8 + kk + 2) * 512 + lane * 8];
            u16x8 af[2];
#pragma unroll
            for (int i = 0; i < 2; i++)
                af[i] = *(const u16x8*)&Os[(16 * i + l16) * 256 + (((kk * 4 + quad) ^ (l16 & 7)) << 3)];
#pragma unroll
            for (int i = 0; i < 2; i++)
#pragma unroll
                for (int j = 0; j < 4; j++)
                    accO[i][j] = mfma_bf16(af[i], bf[kk % 3][j], accO[i][j]);
        }
    }
    __syncthreads();   // Os reads done -> stats alias safe

    // ---- phase 2: residual + LN1 -> zout ----
    float bb[4], gg[4], bt[4];
#pragma unroll
    for (int j = 0; j < 4; j++) {
        int col = 64 * wave + 16 * j + l16;
        bb[j] = bo[col]; gg[j] = g1[col]; bt[j] = be1[col];
    }
#pragma unroll
    for (int i = 0; i < 2; i++)
#pragma unroll
        for (int r = 0; r < 4; r++) {
            int row = 16 * i + quad * 4 + r;
            float s1 = 0.f, s2 = 0.f;
#pragma unroll
            for (int j = 0; j < 4; j++) {
                int col = 64 * wave + 16 * j + l16;
                float v = accO[i][j][r] + bb[j] + b2f(Zs[zadr(row, col)]);
                accO[i][j][r] = v; s1 += v; s2 += v * v;
            }
            for (int mk = 1; mk < 16; mk <<= 1) { s1 += __shfl_xor(s1, mk); s2 += __shfl_xor(s2, mk); }
            if (l16 == 0) stats[row * 4 + wave] = make_float2(s1, s2);
        }
    __syncthreads();
#pragma unroll
    for (int i = 0; i < 2; i++)
#pragma unroll
        for (int r = 0; r < 4; r++) {
            int row = 16 * i + quad * 4 + r;
            f32x4 p0 = *(const f32x4*)&stats[row * 4];
            f32x4 p1 = *(const f32x4*)&stats[row * 4 + 2];
            float S1 = p0[0] + p0[2] + p1[0] + p1[2];
            float S2 = p0[1] + p0[3] + p1[1] + p1[3];
            float mean = S1 * (1.0f / 256.0f);
            float var  = S2 * (1.0f / 256.0f) - mean * mean;
            float rstd = rsqrtf(var + 1e-5f);
            long grow = m_blk + row;
#pragma unroll
            for (int j = 0; j < 4; j++) {
                int col = 64 * wave + 16 * j + l16;
                zout[grow * 256 + col] = f2b((accO[i][j][r] - mean) * rstd * gg[j] + bt[j]);
            }
        }
}

// ---------------- fused FFN (+ next-layer QKV tail): 32-row tiles, SEQUENTIAL phases ----------------
// Round-11 structure (48KB LDS, Zs+full-h1 Hs; best measured) + ring-3 B prefetch.
template <int LAST>
__global__ __launch_bounds__(256, 2) void k_ffn(
    const unsigned short* __restrict__ zin,      // post-LN1 z
    const unsigned short* __restrict__ wp1, const float* __restrict__ b1,
    const unsigned short* __restrict__ wp2, const float* __restrict__ b2,
    const float* __restrict__ g2, const float* __restrict__ be2,
    unsigned short* __restrict__ zout, float* __restrict__ outF,
    const unsigned short* __restrict__ wpQ, const float* __restrict__ bqn,
    unsigned short* __restrict__ qkhn, unsigned short* __restrict__ vcurn) {
    __shared__ unsigned short Zs[32 * 256];    // z tile (swizzled), 16 KB
    __shared__ unsigned short Hs[32 * 512];    // FULL gelu(h1) tile (swizzled), 32 KB
    float2* stats = (float2*)Hs;               // alias after GEMM2 consumes Hs

    const int tid  = threadIdx.x;
    const int wave = tid >> 6, lane = tid & 63, quad = (lane >> 4) & 3, l16 = lane & 15;
    const int m_blk = blockIdx.x * 32;

    // ---- stage z tile (vector load -> swizzled LDS) ----
#pragma unroll
    for (int s = 0; s < 4; s++) {
        int c = tid + 256 * s;
        int zr = c >> 5, zc = (c & 31) * 8;
        u16x8 v = *(const u16x8*)&zin[(long)(m_blk + zr) * 256 + zc];
        *(u16x8*)&Zs[zadr(zr, zc)] = v;
    }
    __syncthreads();

    // ---- phase 1: GEMM1, two 256-col passes (ring-3 B prefetch, no barrier) ----
#pragma unroll 1
    for (int c = 0; c < 2; c++) {
        f32x4 a1[2][4] = {};
        u16x8 bf[3][4];
#pragma unroll
        for (int j = 0; j < 4; j++) {
            bf[0][j] = *(const u16x8*)&wp1[((long)(16 * c + 4 * wave + j) * 8 + 0) * 512 + lane * 8];
            bf[1][j] = *(const u16x8*)&wp1[((long)(16 * c + 4 * wave + j) * 8 + 1) * 512 + lane * 8];
        }
#pragma unroll
        for (int kk = 0; kk < 8; kk++) {
            if (kk < 6)
#pragma unroll
                for (int j = 0; j < 4; j++)
                    bf[(kk + 2) % 3][j] = *(const u16x8*)&wp1[((long)(16 * c + 4 * wave + j) * 8 + kk + 2) * 512 + lane * 8];
            u16x8 af[2];
#pragma unroll
            for (int i = 0; i < 2; i++)
                af[i] = *(const u16x8*)&Zs[(16 * i + l16) * 256 + (((kk * 4 + quad) ^ (l16 & 7)) << 3)];
#pragma unroll
            for (int i = 0; i < 2; i++)
#pragma unroll
                for (int j = 0; j < 4; j++)
                    a1[i][j] = mfma_bf16(af[i], bf[kk % 3][j], a1[i][j]);
        }
        // bias + gelu -> Hs (swizzled, 512-col rows)
        float b1v[4];
#pragma unroll
        for (int j = 0; j < 4; j++) b1v[j] = b1[256 * c + 64 * wave + 16 * j + l16];
#pragma unroll
        for (int i = 0; i < 2; i++)
#pragma unroll
            for (int j = 0; j < 4; j++)
#pragma unroll
                for (int r = 0; r < 4; r++) {
                    int row  = 16 * i + quad * 4 + r;
                    int colh = 256 * c + 64 * wave + 16 * j + l16;
                    float v = a1[i][j][r] + b1v[j];
                    float gel = 0.5f * v * (1.0f + erff(v * 0.70710678118f));
                    Hs[hadr(row, colh)] = f2b(gel);
                }
    }
    __syncthreads();   // full h1 visible

    // ---- phase 2: GEMM2, K=512 single loop (ring-3 B prefetch) ----
    f32x4 z2[2][4] = {};
    {
        u16x8 bg[3][4];
#pragma unroll
        for (int j = 0; j < 4; j++) {
            bg[0][j] = *(const u16x8*)&wp2[((long)(4 * wave + j) * 16 + 0) * 512 + lane * 8];
            bg[1][j] = *(const u16x8*)&wp2[((long)(4 * wave + j) * 16 + 1) * 512 + lane * 8];
        }
#pragma unroll
        for (int kk = 0; kk < 16; kk++) {
            if (kk < 14)
#pragma unroll
                for (int j = 0; j < 4; j++)
                    bg[(kk + 2) % 3][j] = *(const u16x8*)&wp2[((long)(4 * wave + j) * 16 + kk + 2) * 512 + lane * 8];
            u16x8 af[2];
#pragma unroll
            for (int i = 0; i < 2; i++)
                af[i] = *(const u16x8*)&Hs[(16 * i + l16) * 512 + (((kk * 4 + quad) ^ (l16 & 7)) << 3)];
#pragma unroll
            for (int i = 0; i < 2; i++)
#pragma unroll
                for (int j = 0; j < 4; j++)
                    z2[i][j] = mfma_bf16(af[i], bg[kk % 3][j], z2[i][j]);
        }
    }
    __syncthreads();   // Hs reads done -> stats alias safe

    // ---- phase 3: residual + LN2 ----
    float b2v[4], gg[4], bb[4];
#pragma unroll
    for (int j = 0; j < 4; j++) {
        int col = 64 * wave + 16 * j + l16;
        b2v[j] = b2[col]; gg[j] = g2[col]; bb[j] = be2[col];
    }
#pragma unroll
    for (int i = 0; i < 2; i++)
#pragma unroll
        for (int r = 0; r < 4; r++) {
            int row = 16 * i + quad * 4 + r;
            float s1 = 0.f, s2 = 0.f;
#pragma unroll
            for (int j = 0; j < 4; j++) {
                int col = 64 * wave + 16 * j + l16;
                float v = z2[i][j][r] + b2v[j] + b2f(Zs[zadr(row, col)]);
                z2[i][j][r] = v; s1 += v; s2 += v * v;
            }
            for (int mk = 1; mk < 16; mk <<= 1) { s1 += __shfl_xor(s1, mk); s2 += __shfl_xor(s2, mk); }
            if (l16 == 0) stats[row * 4 + wave] = make_float2(s1, s2);
        }
    __syncthreads();
#pragma unroll
    for (int i = 0; i < 2; i++)
#pragma unroll
        for (int r = 0; r < 4; r++) {
            int row = 16 * i + quad * 4 + r;
            f32x4 p0 = *(const f32x4*)&stats[row * 4];
            f32x4 p1 = *(const f32x4*)&stats[row * 4 + 2];
            float S1 = p0[0] + p0[2] + p1[0] + p1[2];
            float S2 = p0[1] + p0[3] + p1[1] + p1[3];
            float mean = S1 * (1.0f / 256.0f);
            float var  = S2 * (1.0f / 256.0f) - mean * mean;
            float rstd = rsqrtf(var + 1e-5f);
            long grow = m_blk + row;
#pragma unroll
            for (int j = 0; j < 4; j++) {
                int col = 64 * wave + 16 * j + l16;
                float o = (z2[i][j][r] - mean) * rstd * gg[j] + bb[j];
                if constexpr (LAST) {
                    outF[grow * 256 + col] = o;
                } else {
                    unsigned short hv = f2b(o);
                    Zs[zadr(row, col)] = hv;        // keep post-LN2 z resident for QKV
                    zout[grow * 256 + col] = hv;
                }
            }
        }

    if constexpr (!LAST) {
        __syncthreads();   // Zs now holds post-LN2 z
        // ---- phase 4: QKV_{l+1}, 3 passes of 256 cols (ring-3 B prefetch) ----
        const int bb_ = m_blk >> 7;               // batch
        const int rbase = m_blk & 127;            // row offset within batch
#pragma unroll 1
        for (int p = 0; p < 3; p++) {
            f32x4 aq[2][4] = {};
            {
                u16x8 bf[3][4];
#pragma unroll
                for (int j = 0; j < 4; j++) {
                    bf[0][j] = *(const u16x8*)&wpQ[((long)(16 * p + 4 * wave + j) * 8 + 0) * 512 + lane * 8];
                    bf[1][j] = *(const u16x8*)&wpQ[((long)(16 * p + 4 * wave + j) * 8 + 1) * 512 + lane * 8];
                }
#pragma unroll
                for (int kk = 0; kk < 8; kk++) {
                    if (kk < 6)
#pragma unroll
                        for (int j = 0; j < 4; j++)
                            bf[(kk + 2) % 3][j] = *(const u16x8*)&wpQ[((long)(16 * p + 4 * wave + j) * 8 + kk + 2) * 512 + lane * 8];
                    u16x8 af[2];
#pragma unroll
                    for (int i = 0; i < 2; i++)
                        af[i] = *(const u16x8*)&Zs[(16 * i + l16) * 256 + (((kk * 4 + quad) ^ (l16 & 7)) << 3)];
#pragma unroll
                    for (int i = 0; i < 2; i++)
#pragma unroll
                        for (int j = 0; j < 4; j++)
                            aq[i][j] = mfma_bf16(af[i], bf[kk % 3][j], aq[i][j]);
                }
            }
            // epilogue: q/k -> head-major qk history; v -> head-major [h][row][dk]
#pragma unroll
            for (int j = 0; j < 4; j++) {
                int col = 256 * p + 64 * wave + 16 * j + l16;
                float bqv = bqn[col];
                int h = 4 * wave + j;                         // head (uniform per wave,j)
                if (p < 2) {
                    unsigned short* qk = qkhn + ((long)((bb_ * 16 + h) * 2 + p)) * 2048;
#pragma unroll
                    for (int i = 0; i < 2; i++)
#pragma unroll
                        for (int r = 0; r < 4; r++) {
                            int rin = rbase + 16 * i + quad * 4 + r;
                            qk[rin * 16 + l16] = f2b(aq[i][j][r] + bqv);
                        }
                } else {
#pragma unroll
                    for (int i = 0; i < 2; i++)
#pragma unroll
                        for (int r = 0; r < 4; r++) {
                            long grow = m_blk + 16 * i + quad * 4 + r;
                            vcurn[((long)h * ROWS + grow) * 16 + l16] = f2b(aq[i][j][r] + bqv);
                        }
                }
            }
        }
    }
}

// ---------------- fused attention for layer L (score-carry recompute) ----------------
template <int L>
__global__ __launch_bounds__(256) void k_attn(const unsigned short* __restrict__ qkh,
                                              const unsigned short* __restrict__ vbuf,
                                              const float* __restrict__ pb,
                                              unsigned short* __restrict__ o_out) {
    __shared__ unsigned short vt[16 * 136];   // v^T [dk][key]; reused to stage o
    __shared__ unsigned short Ps[128 * 136];  // unnormalized probs, ld 136
    const int tid  = threadIdx.x;
    const int wave = tid >> 6, lane = tid & 63, quad = lane >> 4, l16 = lane & 15;
    const int b = blockIdx.x >> 4, h = blockIdx.x & 15;
    const int qrow = tid >> 1, half = tid & 1;

    u16x8 vv = *(const u16x8*)(vbuf + ((long)h * ROWS + b * Qs + qrow) * 16 + half * 8);
    const float* pbt = pb + (long)L * 16384 + tid;

    f32x4 accS[2][8] = {};
    u16x8 zero = {};

    constexpr int FULL = (L + 1) / 2;
    constexpr bool HALF = ((L + 1) & 1) != 0;

#pragma unroll
    for (int p = 0; p < FULL; p++) {
        const unsigned short* q0 = qkh + ((long)(((2 * p) * Bq + b) * 16 + h) * 2) * 2048;
        const unsigned short* q1 = qkh + ((long)(((2 * p + 1) * Bq + b) * 16 + h) * 2) * 2048;
        const unsigned short* qsel = (quad < 2) ? q0 : q1;
        const unsigned short* ksel = (quad < 2) ? (q0 + 2048) : (q1 + 2048);
        const int koff = (quad & 1) * 8;
        u16x8 af[2], bf8[8];
#pragma unroll
        for (int i = 0; i < 2; i++) {
            int m = 32 * wave + 16 * i + l16;
            af[i] = *(const u16x8*)(qsel + m * 16 + koff);
        }
#pragma unroll
        for (int j = 0; j < 8; j++) {
            int n = 16 * j + l16;
            bf8[j] = *(const u16x8*)(ksel + n * 16 + koff);
        }
#pragma unroll
        for (int i = 0; i < 2; i++)
#pragma unroll
            for (int j = 0; j < 8; j++)
                accS[i][j] = mfma_bf16(af[i], bf8[j], accS[i][j]);
    }
    if (HALF) {
        const unsigned short* qt = qkh + ((long)((L * Bq + b) * 16 + h) * 2) * 2048;
        const unsigned short* kt = qt + 2048;
        u16x8 af[2], bf8[8];
#pragma unroll
        for (int i = 0; i < 2; i++) {
            int m = 32 * wave + 16 * i + l16;
            af[i] = (quad < 2) ? *(const u16x8*)(qt + m * 16 + quad * 8) : zero;
        }
#pragma unroll
        for (int j = 0; j < 8; j++) {
            int n = 16 * j + l16;
            bf8[j] = (quad < 2) ? *(const u16x8*)(kt + n * 16 + quad * 8) : zero;
        }
#pragma unroll
        for (int i = 0; i < 2; i++)
#pragma unroll
            for (int j = 0; j < 8; j++)
                accS[i][j] = mfma_bf16(af[i], bf8[j], accS[i][j]);
    }

#pragma unroll
    for (int jj = 0; jj < 8; jj++) vt[(half * 8 + jj) * 136 + qrow] = vv[jj];

#pragma unroll
    for (int i = 0; i < 2; i++) {
#pragma unroll
        for (int r = 0; r < 4; r++) {
            int m = 32 * wave + 16 * i + quad * 4 + r;
#pragma unroll
            for (int j = 0; j < 8; j++) {
                int u = (i * 4 + r) * 8 + j;
                float s = accS[i][j][r] + pbt[u * 256];
                Ps[m * 136 + 16 * j + l16] = f2b(__expf(s));
            }
        }
    }
    __syncthreads();

    f32x4 accO[2] = {};
    f32x4 accR[2] = {};
    u16x8 ones;
#pragma unroll
    for (int jj = 0; jj < 8; jj++) ones[jj] = 0x3F80;
#pragma unroll
    for (int s = 0; s < 4; s++) {
        u16x8 bv = *(const u16x8*)&vt[l16 * 136 + s * 32 + quad * 8];
#pragma unroll
        for (int i = 0; i < 2; i++) {
            u16x8 ap = *(const u16x8*)&Ps[(32 * wave + 16 * i + l16) * 136 + s * 32 + quad * 8];
            accO[i] = mfma_bf16(ap, bv, accO[i]);
            accR[i] = mfma_bf16(ap, ones, accR[i]);
        }
    }
    __syncthreads();
#pragma unroll
    for (int i = 0; i < 2; i++)
#pragma unroll
        for (int r = 0; r < 4; r++) {
            int m = 32 * wave + 16 * i + quad * 4 + r;
            float inv = __builtin_amdgcn_rcpf(accR[i][r]);
            vt[m * 16 + l16] = f2b(accO[i][r] * inv);
        }
    __syncthreads();
    {
        unsigned short* obase = o_out + ((long)h * ROWS + b * Qs) * 16;
        *(u16x8*)&obase[tid * 8] = *(const u16x8*)&vt[tid * 8];
    }
}

extern "C" void kernel_launch(void* const* d_in, const int* in_sizes, int n_in,
                              void* d_out, int out_size, void* d_ws, size_t ws_size,
                              hipStream_t stream) {
    const float* x     = (const float*)d_in[0];
    const float* abias = (const float*)d_in[1];
    const float* WP    = (const float*)d_in[2];
    const float* bP    = (const float*)d_in[3];
    const float* Wpos  = (const float*)d_in[4];
    const float* Wq    = (const float*)d_in[5];
    const float* bqp   = (const float*)d_in[6];
    const float* Wk    = (const float*)d_in[7];
    const float* bkp   = (const float*)d_in[8];
    const float* Wv    = (const float*)d_in[9];
    const float* bvp   = (const float*)d_in[10];
    const float* Wo    = (const float*)d_in[11];
    const float* bo    = (const float*)d_in[12];
    const float* g1    = (const float*)d_in[13];
    const float* be1   = (const float*)d_in[14];
    const float* W1    = (const float*)d_in[15];
    const float* b1    = (const float*)d_in[16];
    const float* W2    = (const float*)d_in[17];
    const float* b2    = (const float*)d_in[18];
    const float* g2    = (const float*)d_in[19];
    const float* be2   = (const float*)d_in[20];
    (void)in_sizes; (void)n_in; (void)out_size; (void)ws_size;

    char* ws = (char*)d_ws;
    size_t off = 0;
    auto alloc = [&](size_t bytes) -> char* {
        char* p = ws + off; off += (bytes + 255) & ~(size_t)255; return p;
    };
    unsigned short* z_b   = (unsigned short*)alloc((size_t)ROWS * Dm * 2);      // 16.8 MB
    unsigned short* qkh   = (unsigned short*)alloc((size_t)3 * ROWS * 512 * 2); // 100.7 MB head-major
    unsigned short* v_cur = (unsigned short*)alloc((size_t)ROWS * Dm * 2);      // 16.8 MB head-major
    unsigned short* o_b   = (unsigned short*)alloc((size_t)ROWS * Dm * 2);      // 16.8 MB head-major
    unsigned short* wTqkv = (unsigned short*)alloc((size_t)S0a * 2);
    unsigned short* wpQ   = (unsigned short*)alloc((size_t)S0b * 2);
    unsigned short* wpO   = (unsigned short*)alloc((size_t)S1 * 2);
    unsigned short* wp1   = (unsigned short*)alloc((size_t)S2 * 2);
    unsigned short* wp2   = (unsigned short*)alloc((size_t)S3 * 2);
    float*          bqkv  = (float*)alloc((size_t)S4 * 4);
    float*          pb    = (float*)alloc((size_t)S5 * 4);

    k_prep<<<(PREP_TOT + 255) / 256, 256, 0, stream>>>(
        Wq, Wk, Wv, Wo, W1, W2, bqp, bkp, bvp, abias,
        wTqkv, wpQ, wpO, wp1, wp2, bqkv, pb);
    k_embed<<<ROWS, 256, 0, stream>>>(x, WP, bP, Wpos, z_b);

    // layer-0 QKV on the proven 2-barrier GEMM
    k_gemm<0, 2><<<dim3(ROWS / 128, 6), 256, 0, stream>>>(
        z_b, wTqkv, bqkv, qkh, v_cur, ROWS, 768, 256);

    for (int l = 0; l < 3; l++) {
        // attention with score-carry recompute (layer-packed K)
        if (l == 0)      k_attn<0><<<Bq * 16, 256, 0, stream>>>(qkh, v_cur, pb, o_b);
        else if (l == 1) k_attn<1><<<Bq * 16, 256, 0, stream>>>(qkh, v_cur, pb, o_b);
        else             k_attn<2><<<Bq * 16, 256, 0, stream>>>(qkh, v_cur, pb, o_b);
        // O projection + residual + LN1: zero-barrier frag-major
        k_oln<<<ROWS / 32, 256, 0, stream>>>(
            z_b, o_b, wpO + (long)l * 65536, bo + l * 256,
            g1 + l * 256, be1 + l * 256, z_b);
        // fused FFN + LN2 (+ next-layer QKV tail); last layer writes f32 d_out
        if (l < 2)
            k_ffn<0><<<ROWS / 32, 256, 0, stream>>>(
                z_b, wp1 + (long)l * 131072, b1 + l * 512,
                wp2 + (long)l * 131072, b2 + l * 256,
                g2 + l * 256, be2 + l * 256, z_b, nullptr,
                wpQ + (long)(l + 1) * 196608, bqkv + (l + 1) * 768,
                qkh + (long)(l + 1) * QK_LSTR, v_cur);
        else
            k_ffn<1><<<ROWS / 32, 256, 0, stream>>>(
                z_b, wp1 + (long)l * 131072, b1 + l * 512,
                wp2 + (long)l * 131072, b2 + l * 256,
                g2 + l * 256, be2 + l * 256, nullptr, (float*)d_out,
                nullptr, nullptr, nullptr, nullptr);
    }
}

// Round 14
// 470.275 us; speedup vs baseline: 1.0401x; 1.0291x over previous
//
#include <hip/hip_runtime.h>

#define DEV __device__ __forceinline__

typedef float          f32x4  __attribute__((ext_vector_type(4)));
typedef __bf16         bf16x8 __attribute__((ext_vector_type(8)));
typedef unsigned short u16x8  __attribute__((ext_vector_type(8)));

static constexpr int  Bq   = 256;   // batch
static constexpr int  Qs   = 128;   // seq len
static constexpr int  Dm   = 256;   // model dim
static constexpr int  Ff   = 512;   // ffn dim
static constexpr int  ROWS = Bq * Qs;               // 32768
static constexpr long QK_LSTR = (long)ROWS * 512;   // q||k history per layer (head-major)

DEV float b2f(unsigned short h) {
    unsigned int u = ((unsigned int)h) << 16;
    float f; __builtin_memcpy(&f, &u, 4); return f;
}
DEV unsigned short f2b(float f) {
    unsigned int u; __builtin_memcpy(&u, &f, 4);
    u += 0x7fffu + ((u >> 16) & 1u);   // RNE
    return (unsigned short)(u >> 16);
}
DEV f32x4 mfma_bf16(u16x8 a, u16x8 b, f32x4 c) {
    return __builtin_amdgcn_mfma_f32_16x16x32_bf16(
        __builtin_bit_cast(bf16x8, a), __builtin_bit_cast(bf16x8, b), c, 0, 0, 0);
}
// async global->LDS, 16B per lane; LDS dst must be wave-uniform base + lane*16
DEV void gl_lds16(const unsigned short* g, unsigned short* l) {
    __builtin_amdgcn_global_load_lds(
        (const __attribute__((address_space(1))) unsigned int*)g,
        (__attribute__((address_space(3))) unsigned int*)l, 16, 0, 0);
}
// XOR-chunk-swizzled LDS address (shorts) for [*][256] bf16 tile; conflict-free
// ds_read_b128 when 16 lanes read 16 consecutive rows at the same column.
DEV int zadr(int row, int col) {
    return row * 256 + ((((col >> 3) ^ (row & 7))) << 3) + (col & 7);
}
// same for [*][512] tiles
DEV int hadr(int row, int col) {
    return row * 512 + ((((col >> 3) ^ (row & 7))) << 3) + (col & 7);
}

// ---------------- one-shot prep + embed (merged: independent work, one dispatch) ----------------
// wTqkv: row-major [n][k] transpose (k_gemm layer-0 QKV).
// wpO/wpQ/wp1/wp2: FRAGMENT-MAJOR packs: for each 16(n) x 32(k) MFMA B-tile, the 64
// lanes' u16x8 fragments stored contiguously (512 shorts = 1KB/wave read).
// lane = quad*16+l16; n = ntile*16+(lane&15); k = kk*32+(lane>>4)*8+e.
static constexpr int S0a = 3 * 768 * 256;  // wTqkv [l][n(768)][k(256)], q-part scaled 0.25
static constexpr int S0b = 3 * 768 * 256;  // wpQ   fragment-major, ntile(48) x kk(8), q scaled
static constexpr int S1  = 3 * 256 * 256;  // wpO   fragment-major, ntile(16) x kk(8)
static constexpr int S2  = 3 * 512 * 256;  // wp1   fragment-major, ntile(32) x kk(8)
static constexpr int S3  = 3 * 256 * 512;  // wp2   fragment-major, ntile(16) x kslice(16)
static constexpr int S4  = 3 * 768;        // bqkv f32, q-part scaled 0.25
static constexpr int S5  = 3 * 64 * 256;   // pb: packed attn bias, [l][u(64)][tid(256)]
static constexpr int PREP_TOT    = S0a + S0b + S1 + S2 + S3 + S4 + S5;
static constexpr int PREP_BLOCKS = (PREP_TOT + 255) / 256;

__global__ void k_prep(const float* __restrict__ Wq, const float* __restrict__ Wk,
                       const float* __restrict__ Wv, const float* __restrict__ Wo,
                       const float* __restrict__ W1, const float* __restrict__ W2,
                       const float* __restrict__ bq, const float* __restrict__ bk,
                       const float* __restrict__ bv, const float* __restrict__ ab,
                       unsigned short* __restrict__ wTqkv, unsigned short* __restrict__ wpQ,
                       unsigned short* __restrict__ wpO,
                       unsigned short* __restrict__ wp1, unsigned short* __restrict__ wp2,
                       float* __restrict__ bqkv, float* __restrict__ pb,
                       const float* __restrict__ x, const float* __restrict__ WP,
                       const float* __restrict__ bP, const float* __restrict__ Wpos,
                       unsigned short* __restrict__ zb) {
    if (blockIdx.x >= PREP_BLOCKS) {
        // ---- embed: z = x @ W_P + b_P + W_pos (KEEP massively parallel: round-9 lesson) ----
        int row = blockIdx.x - PREP_BLOCKS;  // b*Q + q
        int d   = threadIdx.x;               // 0..255
        int q   = row & (Qs - 1);
        const float* xr = x + row * 16;
        float acc = bP[d] + Wpos[q * Dm + d];
#pragma unroll
        for (int p = 0; p < 16; p++) acc += xr[p] * WP[p * Dm + d];
        zb[(long)row * Dm + d] = f2b(acc);
        return;
    }
    int idx = blockIdx.x * 256 + threadIdx.x;
    if (idx < S0a) {
        int l = idx / (768 * 256), r = idx % (768 * 256);
        int n = r / 256, k = r % 256;
        const float* W = (n < 256) ? Wq : (n < 512) ? Wk : Wv;
        float v = W[(long)l * 65536 + k * 256 + (n & 255)];
        if (n < 256) v *= 0.25f;            // fold DK^-0.5 into q
        wTqkv[idx] = f2b(v);
    } else if (idx < S0a + S0b) {
        int j = idx - S0a;
        int l = j / 196608, r = j % 196608;
        int tile = r >> 9, le = r & 511, lane = le >> 3, e = le & 7;
        int ntile = tile >> 3, kk = tile & 7;
        int n = ntile * 16 + (lane & 15), k = kk * 32 + (lane >> 4) * 8 + e;
        float v;
        if (n < 256)      v = Wq[(long)l * 65536 + k * 256 + n] * 0.25f;
        else if (n < 512) v = Wk[(long)l * 65536 + k * 256 + (n - 256)];
        else              v = Wv[(long)l * 65536 + k * 256 + (n - 512)];
        wpQ[j] = f2b(v);
    } else if (idx < S0a + S0b + S1) {
        int j = idx - S0a - S0b;
        int l = j / 65536, r = j % 65536;
        int tile = r >> 9, le = r & 511, lane = le >> 3, e = le & 7;
        int ntile = tile >> 3, kk = tile & 7;
        int n = ntile * 16 + (lane & 15), k = kk * 32 + (lane >> 4) * 8 + e;
        wpO[j] = f2b(Wo[(long)l * 65536 + k * 256 + n]);
    } else if (idx < S0a + S0b + S1 + S2) {
        int j = idx - S0a - S0b - S1;
        int l = j / 131072, r = j % 131072;
        int tile = r >> 9, le = r & 511, lane = le >> 3, e = le & 7;
        int ntile = tile >> 3, kk = tile & 7;
        int n = ntile * 16 + (lane & 15), k = kk * 32 + (lane >> 4) * 8 + e;
        wp1[j] = f2b(W1[(long)l * 131072 + k * 512 + n]);
    } else if (idx < S0a + S0b + S1 + S2 + S3) {
        int j = idx - S0a - S0b - S1 - S2;
        int l = j / 131072, r = j % 131072;
        int tile = r >> 9, le = r & 511, lane = le >> 3, e = le & 7;
        int ntile = tile >> 4, kk = tile & 15;              // K=512 -> 16 k-slices
        int n = ntile * 16 + (lane & 15), k = kk * 32 + (lane >> 4) * 8 + e;
        wp2[j] = f2b(W2[(long)l * 131072 + k * 256 + n]);
    } else if (idx < S0a + S0b + S1 + S2 + S3 + S4) {
        int j = idx - S0a - S0b - S1 - S2 - S3;
        int l = j / 768, c = j % 768;
        float v = (c < 256) ? bq[l * 256 + c] * 0.25f
                : (c < 512) ? bk[l * 256 + c - 256]
                            : bv[l * 256 + c - 512];
        bqkv[j] = v;
    } else if (idx < PREP_TOT) {
        int j = idx - S0a - S0b - S1 - S2 - S3 - S4;
        int l = j / 16384, r = j % 16384;
        int u = r / 256, t = r % 256;
        int i = u >> 5, rr = (u >> 3) & 3, jj = u & 7;
        int wave = t >> 6, quad = (t >> 4) & 3, l16 = t & 15;
        int m = 32 * wave + 16 * i + 4 * quad + rr;
        int col = 16 * jj + l16;
        pb[j] = (float)(l + 1) * ab[m * 128 + col];
    }
}

// ---------------- GEMM (layer-0 QKV): C = A @ W + bias, W as WT[NxK] bf16 ----------------
// 128x128 tile, 4 waves 2x2, two BK=32 sub-tiles per barrier; LDS-staged coalesced epilogue.
// MODE 2 = qkv split: col<512 -> head-major qk history, col>=512 -> v head-major [h][grow][dk]
template <int GELU, int MODE>
__global__ __launch_bounds__(256) void k_gemm(const unsigned short* __restrict__ A,
                                              const unsigned short* __restrict__ WT,
                                              const float* __restrict__ bias,
                                              unsigned short* __restrict__ outB,
                                              unsigned short* __restrict__ aux,
                                              int M, int N, int K) {
    __shared__ unsigned short smem[16384];     // As[2][4096] | Bs[2][4096]; C-stage after
    unsigned short* As = smem;
    unsigned short* Bs = smem + 8192;
    const int tid  = threadIdx.x;
    const int wave = tid >> 6, lane = tid & 63, quad = lane >> 4, l16 = lane & 15;
    const int mq = wave >> 1, nq = wave & 1;
    const int m_blk = blockIdx.x * 128, n_blk = blockIdx.y * 128;
    const int c0 = tid, c1 = tid + 256;
    const int ra0 = c0 >> 2, ca0 = (c0 & 3) * 8;
    const int ra1 = c1 >> 2, ca1 = (c1 & 3) * 8;

    f32x4 acc[4][4] = {};

    for (int k0 = 0; k0 < K; k0 += 64) {
#pragma unroll
        for (int hh = 0; hh < 2; hh++) {
            int kk = k0 + hh * 32;
            gl_lds16(A  + (long)(m_blk + ra0) * K + kk + ca0, &As[hh * 4096 + c0 * 8]);
            gl_lds16(A  + (long)(m_blk + ra1) * K + kk + ca1, &As[hh * 4096 + c1 * 8]);
            gl_lds16(WT + (long)(n_blk + ra0) * K + kk + ca0, &Bs[hh * 4096 + c0 * 8]);
            gl_lds16(WT + (long)(n_blk + ra1) * K + kk + ca1, &Bs[hh * 4096 + c1 * 8]);
        }
        __syncthreads();
#pragma unroll
        for (int hh = 0; hh < 2; hh++) {
            u16x8 af[4], bf[4];
#pragma unroll
            for (int i = 0; i < 4; i++)
                af[i] = *(const u16x8*)&As[hh * 4096 + (64 * mq + 16 * i + l16) * 32 + quad * 8];
#pragma unroll
            for (int j = 0; j < 4; j++)
                bf[j] = *(const u16x8*)&Bs[hh * 4096 + (64 * nq + 16 * j + l16) * 32 + quad * 8];
#pragma unroll
            for (int i = 0; i < 4; i++)
#pragma unroll
                for (int j = 0; j < 4; j++)
                    acc[i][j] = mfma_bf16(af[i], bf[j], acc[i][j]);
        }
        __syncthreads();
    }

#pragma unroll
    for (int i = 0; i < 4; i++) {
        int rl = 64 * mq + 16 * i + quad * 4;
#pragma unroll
        for (int j = 0; j < 4; j++) {
            int cl = 64 * nq + 16 * j + l16;
            float bb = bias[n_blk + cl];
#pragma unroll
            for (int r = 0; r < 4; r++) {
                float v = acc[i][j][r] + bb;
                if (GELU) v = 0.5f * v * (1.0f + erff(v * 0.70710678118f));
                if (MODE == 0) smem[(rl + r) * 128 + cl] = f2b(v);
                if (MODE == 2) {
                    int g = 4 * nq + j;                      // 16-col subtile within block
                    smem[g * 2048 + (rl + r) * 16 + l16] = f2b(v);
                }
            }
        }
    }
    __syncthreads();
#pragma unroll
    for (int c = tid; c < 2048; c += 256) {
        u16x8 val = *(const u16x8*)&smem[c * 8];
        if (MODE == 0) {
            int row = c >> 4, seg = c & 15;
            *(u16x8*)&outB[(long)(m_blk + row) * N + n_blk + seg * 8] = val;
        }
        if (MODE == 2) {
            int g = c >> 8, w = c & 255;                     // subtile, 16B-chunk within 4KB
            int n = n_blk + g * 16;
            if (n < 512) {
                int s = n >> 8, h = (n >> 4) & 15;
                *(u16x8*)&outB[((long)(((m_blk >> 7) * 16 + h) * 2 + s)) * 2048 + w * 8] = val;
            } else {
                int hh = (n - 512) >> 4;
                *(u16x8*)&aux[((long)hh * ROWS + m_blk) * 16 + w * 8] = val;
            }
        }
    }
}

// ---------------- Oproj + residual + LN1: zero-barrier frag-major, 32-row tiles ----------------
// z_b = LN1( z_b + o @ Wo + bo ).  1024 blocks x 256 thr (4 waves), 32KB LDS.
// 1-deep B prefetch (ring-3 measured neutral-to-worse, round 13).
__global__ __launch_bounds__(256, 2) void k_oln(
    const unsigned short* __restrict__ zin,
    const unsigned short* __restrict__ ob,       // attn out, head-major [h][ROWS][16]
    const unsigned short* __restrict__ wpO, const float* __restrict__ bo,
    const float* __restrict__ g1, const float* __restrict__ be1,
    unsigned short* __restrict__ zout) {
    __shared__ unsigned short Zs[32 * 256];    // residual z (swizzled), 16 KB
    __shared__ unsigned short Os[32 * 256];    // o tile (swizzled), 16 KB; stats alias
    float2* stats = (float2*)Os;

    const int tid  = threadIdx.x;
    const int wave = tid >> 6, lane = tid & 63, quad = (lane >> 4) & 3, l16 = lane & 15;
    const int m_blk = blockIdx.x * 32;

    // ---- phase 0: stage z and o ----
#pragma unroll
    for (int s = 0; s < 4; s++) {
        int c = tid + 256 * s;
        int zr = c >> 5, zc = (c & 31) * 8;
        u16x8 vz = *(const u16x8*)&zin[(long)(m_blk + zr) * 256 + zc];
        *(u16x8*)&Zs[zadr(zr, zc)] = vz;
        int h = c >> 6, r = (c >> 1) & 31, hf = c & 1;
        u16x8 vo = *(const u16x8*)&ob[((long)h * ROWS + m_blk + r) * 16 + hf * 8];
        *(u16x8*)&Os[zadr(r, h * 16 + hf * 8)] = vo;
    }
    __syncthreads();

    // ---- phase 1: Oproj accO = o @ Wo (zero-barrier, B prefetched) ----
    f32x4 accO[2][4] = {};
    {
        u16x8 bf[2][4];
#pragma unroll
        for (int j = 0; j < 4; j++)
            bf[0][j] = *(const u16x8*)&wpO[((long)(4 * wave + j) * 8 + 0) * 512 + lane * 8];
#pragma unroll
        for (int kk = 0; kk < 8; kk++) {
            if (kk < 7)
#pragma unroll
                for (int j = 0; j < 4; j++)
                    bf[(kk + 1) & 1][j] = *(const u16x8*)&wpO[((long)(4 * wave + j) * 8 + kk + 1) * 512 + lane * 8];
            u16x8 af[2];
#pragma unroll
            for (int i = 0; i < 2; i++)
                af[i] = *(const u16x8*)&Os[(16 * i + l16) * 256 + (((kk * 4 + quad) ^ (l16 & 7)) << 3)];
#pragma unroll
            for (int i = 0; i < 2; i++)
#pragma unroll
                for (int j = 0; j < 4; j++)
                    accO[i][j] = mfma_bf16(af[i], bf[kk & 1][j], accO[i][j]);
        }
    }
    __syncthreads();   // Os reads done -> stats alias safe

    // ---- phase 2: residual + LN1 -> zout ----
    float bb[4], gg[4], bt[4];
#pragma unroll
    for (int j = 0; j < 4; j++) {
        int col = 64 * wave + 16 * j + l16;
        bb[j] = bo[col]; gg[j] = g1[col]; bt[j] = be1[col];
    }
#pragma unroll
    for (int i = 0; i < 2; i++)
#pragma unroll
        for (int r = 0; r < 4; r++) {
            int row = 16 * i + quad * 4 + r;
            float s1 = 0.f, s2 = 0.f;
#pragma unroll
            for (int j = 0; j < 4; j++) {
                int col = 64 * wave + 16 * j + l16;
                float v = accO[i][j][r] + bb[j] + b2f(Zs[zadr(row, col)]);
                accO[i][j][r] = v; s1 += v; s2 += v * v;
            }
            for (int mk = 1; mk < 16; mk <<= 1) { s1 += __shfl_xor(s1, mk); s2 += __shfl_xor(s2, mk); }
            if (l16 == 0) stats[row * 4 + wave] = make_float2(s1, s2);
        }
    __syncthreads();
#pragma unroll
    for (int i = 0; i < 2; i++)
#pragma unroll
        for (int r = 0; r < 4; r++) {
            int row = 16 * i + quad * 4 + r;
            f32x4 p0 = *(const f32x4*)&stats[row * 4];
            f32x4 p1 = *(const f32x4*)&stats[row * 4 + 2];
            float S1 = p0[0] + p0[2] + p1[0] + p1[2];
            float S2 = p0[1] + p0[3] + p1[1] + p1[3];
            float mean = S1 * (1.0f / 256.0f);
            float var  = S2 * (1.0f / 256.0f) - mean * mean;
            float rstd = rsqrtf(var + 1e-5f);
            long grow = m_blk + row;
#pragma unroll
            for (int j = 0; j < 4; j++) {
                int col = 64 * wave + 16 * j + l16;
                zout[grow * 256 + col] = f2b((accO[i][j][r] - mean) * rstd * gg[j] + bt[j]);
            }
        }
}

// ---------------- fused FFN (+ next-layer QKV tail): 32-row tiles, SEQUENTIAL phases ----------------
// z = LN2( z + gelu(z@W1+b1)@W2 + b2 ); then (non-LAST) QKV_{l+1} from Zs in 3 passes.
// 1024 blocks x 256 thr (4 waves). LDS: Zs 16KB + full-h1 Hs 32KB = 48KB.
// launch_bounds(256,2): VGPR cap 256 -- do NOT starve the allocator (round-4/6 lesson).
// Phases strictly sequential; per-phase live set ~72 regs -> no spill (round-7/11 verified).
// 1-deep B prefetch (ring-3 neutral, round 13); occupancy pinned ~20% regardless of
// LDS 32 vs 48KB (round 12) -> keep the faster 48KB single-region layout.
template <int LAST>
__global__ __launch_bounds__(256, 2) void k_ffn(
    const unsigned short* __restrict__ zin,      // post-LN1 z
    const unsigned short* __restrict__ wp1, const float* __restrict__ b1,
    const unsigned short* __restrict__ wp2, const float* __restrict__ b2,
    const float* __restrict__ g2, const float* __restrict__ be2,
    unsigned short* __restrict__ zout, float* __restrict__ outF,
    const unsigned short* __restrict__ wpQ, const float* __restrict__ bqn,
    unsigned short* __restrict__ qkhn, unsigned short* __restrict__ vcurn) {
    __shared__ unsigned short Zs[32 * 256];    // z tile (swizzled), 16 KB
    __shared__ unsigned short Hs[32 * 512];    // FULL gelu(h1) tile (swizzled), 32 KB
    float2* stats = (float2*)Hs;               // alias after GEMM2 consumes Hs

    const int tid  = threadIdx.x;
    const int wave = tid >> 6, lane = tid & 63, quad = (lane >> 4) & 3, l16 = lane & 15;
    const int m_blk = blockIdx.x * 32;

    // ---- stage z tile (vector load -> swizzled LDS) ----
#pragma unroll
    for (int s = 0; s < 4; s++) {
        int c = tid + 256 * s;
        int zr = c >> 5, zc = (c & 31) * 8;
        u16x8 v = *(const u16x8*)&zin[(long)(m_blk + zr) * 256 + zc];
        *(u16x8*)&Zs[zadr(zr, zc)] = v;
    }
    __syncthreads();

    // ---- phase 1: GEMM1, two 256-col passes (sequential; disjoint Hs writes, no barrier) ----
#pragma unroll 1
    for (int c = 0; c < 2; c++) {
        f32x4 a1[2][4] = {};
        u16x8 bf[2][4];
#pragma unroll
        for (int j = 0; j < 4; j++)
            bf[0][j] = *(const u16x8*)&wp1[((long)(16 * c + 4 * wave + j) * 8 + 0) * 512 + lane * 8];
#pragma unroll
        for (int kk = 0; kk < 8; kk++) {
            if (kk < 7)
#pragma unroll
                for (int j = 0; j < 4; j++)
                    bf[(kk + 1) & 1][j] = *(const u16x8*)&wp1[((long)(16 * c + 4 * wave + j) * 8 + kk + 1) * 512 + lane * 8];
            u16x8 af[2];
#pragma unroll
            for (int i = 0; i < 2; i++)
                af[i] = *(const u16x8*)&Zs[(16 * i + l16) * 256 + (((kk * 4 + quad) ^ (l16 & 7)) << 3)];
#pragma unroll
            for (int i = 0; i < 2; i++)
#pragma unroll
                for (int j = 0; j < 4; j++)
                    a1[i][j] = mfma_bf16(af[i], bf[kk & 1][j], a1[i][j]);
        }
        // bias + gelu -> Hs (swizzled, 512-col rows)
        float b1v[4];
#pragma unroll
        for (int j = 0; j < 4; j++) b1v[j] = b1[256 * c + 64 * wave + 16 * j + l16];
#pragma unroll
        for (int i = 0; i < 2; i++)
#pragma unroll
            for (int j = 0; j < 4; j++)
#pragma unroll
                for (int r = 0; r < 4; r++) {
                    int row  = 16 * i + quad * 4 + r;
                    int colh = 256 * c + 64 * wave + 16 * j + l16;
                    float v = a1[i][j][r] + b1v[j];
                    float gel = 0.5f * v * (1.0f + erff(v * 0.70710678118f));
                    Hs[hadr(row, colh)] = f2b(gel);
                }
    }
    __syncthreads();   // full h1 visible

    // ---- phase 2: GEMM2, K=512 in one barrier-free loop ----
    f32x4 z2[2][4] = {};
    {
        u16x8 bg[2][4];
#pragma unroll
        for (int j = 0; j < 4; j++)
            bg[0][j] = *(const u16x8*)&wp2[((long)(4 * wave + j) * 16 + 0) * 512 + lane * 8];
#pragma unroll
        for (int kk = 0; kk < 16; kk++) {
            if (kk < 15)
#pragma unroll
                for (int j = 0; j < 4; j++)
                    bg[(kk + 1) & 1][j] = *(const u16x8*)&wp2[((long)(4 * wave + j) * 16 + kk + 1) * 512 + lane * 8];
            u16x8 af[2];
#pragma unroll
            for (int i = 0; i < 2; i++)
                af[i] = *(const u16x8*)&Hs[(16 * i + l16) * 512 + (((kk * 4 + quad) ^ (l16 & 7)) << 3)];
#pragma unroll
            for (int i = 0; i < 2; i++)
#pragma unroll
                for (int j = 0; j < 4; j++)
                    z2[i][j] = mfma_bf16(af[i], bg[kk & 1][j], z2[i][j]);
        }
    }
    __syncthreads();   // Hs reads done -> stats alias safe

    // ---- phase 3: residual + LN2 ----
    float b2v[4], gg[4], bb[4];
#pragma unroll
    for (int j = 0; j < 4; j++) {
        int col = 64 * wave + 16 * j + l16;
        b2v[j] = b2[col]; gg[j] = g2[col]; bb[j] = be2[col];
    }
#pragma unroll
    for (int i = 0; i < 2; i++)
#pragma unroll
        for (int r = 0; r < 4; r++) {
            int row = 16 * i + quad * 4 + r;
            float s1 = 0.f, s2 = 0.f;
#pragma unroll
            for (int j = 0; j < 4; j++) {
                int col = 64 * wave + 16 * j + l16;
                float v = z2[i][j][r] + b2v[j] + b2f(Zs[zadr(row, col)]);
                z2[i][j][r] = v; s1 += v; s2 += v * v;
            }
            for (int mk = 1; mk < 16; mk <<= 1) { s1 += __shfl_xor(s1, mk); s2 += __shfl_xor(s2, mk); }
            if (l16 == 0) stats[row * 4 + wave] = make_float2(s1, s2);
        }
    __syncthreads();
#pragma unroll
    for (int i = 0; i < 2; i++)
#pragma unroll
        for (int r = 0; r < 4; r++) {
            int row = 16 * i + quad * 4 + r;
            f32x4 p0 = *(const f32x4*)&stats[row * 4];
            f32x4 p1 = *(const f32x4*)&stats[row * 4 + 2];
            float S1 = p0[0] + p0[2] + p1[0] + p1[2];
            float S2 = p0[1] + p0[3] + p1[1] + p1[3];
            float mean = S1 * (1.0f / 256.0f);
            float var  = S2 * (1.0f / 256.0f) - mean * mean;
            float rstd = rsqrtf(var + 1e-5f);
            long grow = m_blk + row;
#pragma unroll
            for (int j = 0; j < 4; j++) {
                int col = 64 * wave + 16 * j + l16;
                float o = (z2[i][j][r] - mean) * rstd * gg[j] + bb[j];
                if constexpr (LAST) {
                    outF[grow * 256 + col] = o;
                } else {
                    unsigned short hv = f2b(o);
                    Zs[zadr(row, col)] = hv;        // keep post-LN2 z resident for QKV
                    zout[grow * 256 + col] = hv;
                }
            }
        }

    if constexpr (!LAST) {
        __syncthreads();   // Zs now holds post-LN2 z
        // ---- phase 4: QKV_{l+1}, 3 passes of 256 cols (p=0: q, p=1: k, p=2: v) ----
        const int bb_ = m_blk >> 7;               // batch
        const int rbase = m_blk & 127;            // row offset within batch
#pragma unroll 1
        for (int p = 0; p < 3; p++) {
            f32x4 aq[2][4] = {};
            {
                u16x8 bf[2][4];
#pragma unroll
                for (int j = 0; j < 4; j++)
                    bf[0][j] = *(const u16x8*)&wpQ[((long)(16 * p + 4 * wave + j) * 8 + 0) * 512 + lane * 8];
#pragma unroll
                for (int kk = 0; kk < 8; kk++) {
                    if (kk < 7)
#pragma unroll
                        for (int j = 0; j < 4; j++)
                            bf[(kk + 1) & 1][j] = *(const u16x8*)&wpQ[((long)(16 * p + 4 * wave + j) * 8 + kk + 1) * 512 + lane * 8];
                    u16x8 af[2];
#pragma unroll
                    for (int i = 0; i < 2; i++)
                        af[i] = *(const u16x8*)&Zs[(16 * i + l16) * 256 + (((kk * 4 + quad) ^ (l16 & 7)) << 3)];
#pragma unroll
                    for (int i = 0; i < 2; i++)
#pragma unroll
                        for (int j = 0; j < 4; j++)
                            aq[i][j] = mfma_bf16(af[i], bf[kk & 1][j], aq[i][j]);
                }
            }
            // epilogue: q/k -> head-major qk history; v -> head-major [h][row][dk]
#pragma unroll
            for (int j = 0; j < 4; j++) {
                int col = 256 * p + 64 * wave + 16 * j + l16;
                float bqv = bqn[col];
                int h = 4 * wave + j;                         // head (uniform per wave,j)
                if (p < 2) {
                    unsigned short* qk = qkhn + ((long)((bb_ * 16 + h) * 2 + p)) * 2048;
#pragma unroll
                    for (int i = 0; i < 2; i++)
#pragma unroll
                        for (int r = 0; r < 4; r++) {
                            int rin = rbase + 16 * i + quad * 4 + r;
                            qk[rin * 16 + l16] = f2b(aq[i][j][r] + bqv);
                        }
                } else {
#pragma unroll
                    for (int i = 0; i < 2; i++)
#pragma unroll
                        for (int r = 0; r < 4; r++) {
                            long grow = m_blk + 16 * i + quad * 4 + r;
                            vcurn[((long)h * ROWS + grow) * 16 + l16] = f2b(aq[i][j][r] + bqv);
                        }
                }
            }
        }
    }
}

// ---------------- fused attention for layer L (score-carry recompute) ----------------
template <int L>
__global__ __launch_bounds__(256) void k_attn(const unsigned short* __restrict__ qkh,
                                              const unsigned short* __restrict__ vbuf,
                                              const float* __restrict__ pb,
                                              unsigned short* __restrict__ o_out) {
    __shared__ unsigned short vt[16 * 136];   // v^T [dk][key]; reused to stage o
    __shared__ unsigned short Ps[128 * 136];  // unnormalized probs, ld 136
    const int tid  = threadIdx.x;
    const int wave = tid >> 6, lane = tid & 63, quad = lane >> 4, l16 = lane & 15;
    const int b = blockIdx.x >> 4, h = blockIdx.x & 15;
    const int qrow = tid >> 1, half = tid & 1;

    u16x8 vv = *(const u16x8*)(vbuf + ((long)h * ROWS + b * Qs + qrow) * 16 + half * 8);
    const float* pbt = pb + (long)L * 16384 + tid;

    f32x4 accS[2][8] = {};
    u16x8 zero = {};

    constexpr int FULL = (L + 1) / 2;
    constexpr bool HALF = ((L + 1) & 1) != 0;

#pragma unroll
    for (int p = 0; p < FULL; p++) {
        const unsigned short* q0 = qkh + ((long)(((2 * p) * Bq + b) * 16 + h) * 2) * 2048;
        const unsigned short* q1 = qkh + ((long)(((2 * p + 1) * Bq + b) * 16 + h) * 2) * 2048;
        const unsigned short* qsel = (quad < 2) ? q0 : q1;
        const unsigned short* ksel = (quad < 2) ? (q0 + 2048) : (q1 + 2048);
        const int koff = (quad & 1) * 8;
        u16x8 af[2], bf8[8];
#pragma unroll
        for (int i = 0; i < 2; i++) {
            int m = 32 * wave + 16 * i + l16;
            af[i] = *(const u16x8*)(qsel + m * 16 + koff);
        }
#pragma unroll
        for (int j = 0; j < 8; j++) {
            int n = 16 * j + l16;
            bf8[j] = *(const u16x8*)(ksel + n * 16 + koff);
        }
#pragma unroll
        for (int i = 0; i < 2; i++)
#pragma unroll
            for (int j = 0; j < 8; j++)
                accS[i][j] = mfma_bf16(af[i], bf8[j], accS[i][j]);
    }
    if (HALF) {
        const unsigned short* qt = qkh + ((long)((L * Bq + b) * 16 + h) * 2) * 2048;
        const unsigned short* kt = qt + 2048;
        u16x8 af[2], bf8[8];
#pragma unroll
        for (int i = 0; i < 2; i++) {
            int m = 32 * wave + 16 * i + l16;
            af[i] = (quad < 2) ? *(const u16x8*)(qt + m * 16 + quad * 8) : zero;
        }
#pragma unroll
        for (int j = 0; j < 8; j++) {
            int n = 16 * j + l16;
            bf8[j] = (quad < 2) ? *(const u16x8*)(kt + n * 16 + quad * 8) : zero;
        }
#pragma unroll
        for (int i = 0; i < 2; i++)
#pragma unroll
            for (int j = 0; j < 8; j++)
                accS[i][j] = mfma_bf16(af[i], bf8[j], accS[i][j]);
    }

#pragma unroll
    for (int jj = 0; jj < 8; jj++) vt[(half * 8 + jj) * 136 + qrow] = vv[jj];

#pragma unroll
    for (int i = 0; i < 2; i++) {
#pragma unroll
        for (int r = 0; r < 4; r++) {
            int m = 32 * wave + 16 * i + quad * 4 + r;
#pragma unroll
            for (int j = 0; j < 8; j++) {
                int u = (i * 4 + r) * 8 + j;
                float s = accS[i][j][r] + pbt[u * 256];
                Ps[m * 136 + 16 * j + l16] = f2b(__expf(s));
            }
        }
    }
    __syncthreads();

    f32x4 accO[2] = {};
    f32x4 accR[2] = {};
    u16x8 ones;
#pragma unroll
    for (int jj = 0; jj < 8; jj++) ones[jj] = 0x3F80;
#pragma unroll
    for (int s = 0; s < 4; s++) {
        u16x8 bv = *(const u16x8*)&vt[l16 * 136 + s * 32 + quad * 8];
#pragma unroll
        for (int i = 0; i < 2; i++) {
            u16x8 ap = *(const u16x8*)&Ps[(32 * wave + 16 * i + l16) * 136 + s * 32 + quad * 8];
            accO[i] = mfma_bf16(ap, bv, accO[i]);
            accR[i] = mfma_bf16(ap, ones, accR[i]);
        }
    }
    __syncthreads();
#pragma unroll
    for (int i = 0; i < 2; i++)
#pragma unroll
        for (int r = 0; r < 4; r++) {
            int m = 32 * wave + 16 * i + quad * 4 + r;
            float inv = __builtin_amdgcn_rcpf(accR[i][r]);
            vt[m * 16 + l16] = f2b(accO[i][r] * inv);
        }
    __syncthreads();
    {
        unsigned short* obase = o_out + ((long)h * ROWS + b * Qs) * 16;
        *(u16x8*)&obase[tid * 8] = *(const u16x8*)&vt[tid * 8];
    }
}

extern "C" void kernel_launch(void* const* d_in, const int* in_sizes, int n_in,
                              void* d_out, int out_size, void* d_ws, size_t ws_size,
                              hipStream_t stream) {
    const float* x     = (const float*)d_in[0];
    const float* abias = (const float*)d_in[1];
    const float* WP    = (const float*)d_in[2];
    const float* bP    = (const float*)d_in[3];
    const float* Wpos  = (const float*)d_in[4];
    const float* Wq    = (const float*)d_in[5];
    const float* bqp   = (const float*)d_in[6];
    const float* Wk    = (const float*)d_in[7];
    const float* bkp   = (const float*)d_in[8];
    const float* Wv    = (const float*)d_in[9];
    const float* bvp   = (const float*)d_in[10];
    const float* Wo    = (const float*)d_in[11];
    const float* bo    = (const float*)d_in[12];
    const float* g1    = (const float*)d_in[13];
    const float* be1   = (const float*)d_in[14];
    const float* W1    = (const float*)d_in[15];
    const float* b1    = (const float*)d_in[16];
    const float* W2    = (const float*)d_in[17];
    const float* b2    = (const float*)d_in[18];
    const float* g2    = (const float*)d_in[19];
    const float* be2   = (const float*)d_in[20];
    (void)in_sizes; (void)n_in; (void)out_size; (void)ws_size;

    char* ws = (char*)d_ws;
    size_t off = 0;
    auto alloc = [&](size_t bytes) -> char* {
        char* p = ws + off; off += (bytes + 255) & ~(size_t)255; return p;
    };
    unsigned short* z_b   = (unsigned short*)alloc((size_t)ROWS * Dm * 2);      // 16.8 MB
    unsigned short* qkh   = (unsigned short*)alloc((size_t)3 * ROWS * 512 * 2); // 100.7 MB head-major
    unsigned short* v_cur = (unsigned short*)alloc((size_t)ROWS * Dm * 2);      // 16.8 MB head-major
    unsigned short* o_b   = (unsigned short*)alloc((size_t)ROWS * Dm * 2);      // 16.8 MB head-major
    unsigned short* wTqkv = (unsigned short*)alloc((size_t)S0a * 2);
    unsigned short* wpQ   = (unsigned short*)alloc((size_t)S0b * 2);
    unsigned short* wpO   = (unsigned short*)alloc((size_t)S1 * 2);
    unsigned short* wp1   = (unsigned short*)alloc((size_t)S2 * 2);
    unsigned short* wp2   = (unsigned short*)alloc((size_t)S3 * 2);
    float*          bqkv  = (float*)alloc((size_t)S4 * 4);
    float*          pb    = (float*)alloc((size_t)S5 * 4);

    // merged prep + embed (independent work, one dispatch)
    k_prep<<<PREP_BLOCKS + ROWS, 256, 0, stream>>>(
        Wq, Wk, Wv, Wo, W1, W2, bqp, bkp, bvp, abias,
        wTqkv, wpQ, wpO, wp1, wp2, bqkv, pb,
        x, WP, bP, Wpos, z_b);

    // layer-0 QKV on the proven 2-barrier GEMM
    k_gemm<0, 2><<<dim3(ROWS / 128, 6), 256, 0, stream>>>(
        z_b, wTqkv, bqkv, qkh, v_cur, ROWS, 768, 256);

    for (int l = 0; l < 3; l++) {
        // attention with score-carry recompute (layer-packed K)
        if (l == 0)      k_attn<0><<<Bq * 16, 256, 0, stream>>>(qkh, v_cur, pb, o_b);
        else if (l == 1) k_attn<1><<<Bq * 16, 256, 0, stream>>>(qkh, v_cur, pb, o_b);
        else             k_attn<2><<<Bq * 16, 256, 0, stream>>>(qkh, v_cur, pb, o_b);
        // O projection + residual + LN1: zero-barrier frag-major
        k_oln<<<ROWS / 32, 256, 0, stream>>>(
            z_b, o_b, wpO + (long)l * 65536, bo + l * 256,
            g1 + l * 256, be1 + l * 256, z_b);
        // fused FFN + LN2 (+ next-layer QKV tail); last layer writes f32 d_out
        if (l < 2)
            k_ffn<0><<<ROWS / 32, 256, 0, stream>>>(
                z_b, wp1 + (long)l * 131072, b1 + l * 512,
                wp2 + (long)l * 131072, b2 + l * 256,
                g2 + l * 256, be2 + l * 256, z_b, nullptr,
                wpQ + (long)(l + 1) * 196608, bqkv + (l + 1) * 768,
                qkh + (long)(l + 1) * QK_LSTR, v_cur);
        else
            k_ffn<1><<<ROWS / 32, 256, 0, stream>>>(
                z_b, wp1 + (long)l * 131072, b1 + l * 512,
                wp2 + (long)l * 131072, b2 + l * 256,
                g2 + l * 256, be2 + l * 256, nullptr, (float*)d_out,
                nullptr, nullptr, nullptr, nullptr);
    }
}